// Round 1
// baseline (2400.337 us; speedup 1.0000x reference)
//
#include <hip/hip_runtime.h>
#include <hip/hip_bf16.h>
#include <math.h>

#define NB 4
#define NT 4096
#define ND 1024
#define NH 16
#define NDH 64
#define NFF 4096
#define NKK 512
#define NTOK (NB*NKK)          // 2048
#define OUT_MAIN ((size_t)NB*NT*ND)   // 16777216

// ---------------- router: logits + softplus partial sum ----------------
__global__ __launch_bounds__(256)
void router_kernel(const float* __restrict__ hs, const float* __restrict__ wr,
                   float* __restrict__ logits, float* __restrict__ S1)
{
    int wave = threadIdx.x >> 6, lane = threadIdx.x & 63;
    int row = blockIdx.x * 4 + wave;             // 0..16383
    const float4* x4 = (const float4*)(hs + (size_t)row * ND);
    const float4* w4 = (const float4*)wr;
    float acc = 0.f;
#pragma unroll
    for (int i = 0; i < 4; ++i) {
        float4 a = x4[lane + i * 64];
        float4 b = w4[lane + i * 64];
        acc += a.x * b.x + a.y * b.y + a.z * b.z + a.w * b.w;
    }
    for (int off = 32; off; off >>= 1) acc += __shfl_down(acc, off);
    if (lane == 0) {
        logits[row] = acc;
        float sp = fmaxf(acc, 0.f) + log1pf(expf(-fabsf(acc)));
        atomicAdd(S1, sp);
    }
}

// ---------------- per-batch top-k via bitonic sort ----------------
__global__ __launch_bounds__(1024)
void topk_kernel(const float* __restrict__ logits, int* __restrict__ idxv,
                 float* __restrict__ gates, float* __restrict__ S2)
{
    __shared__ unsigned long long keys[NT];
    __shared__ unsigned idx2[NKK];
    int b = blockIdx.x, tid = threadIdx.x;
    const float* lg = logits + (size_t)b * NT;
    for (int i = tid; i < NT; i += 1024) {
        unsigned u = __float_as_uint(lg[i]);
        u ^= (u >> 31) ? 0xFFFFFFFFu : 0x80000000u;  // ascending-sortable
        u = ~u;                                       // descending value
        keys[i] = ((unsigned long long)u << 32) | (unsigned)i;
    }
    __syncthreads();
    for (int k = 2; k <= NT; k <<= 1)
        for (int j = k >> 1; j > 0; j >>= 1) {
            for (int i = tid; i < NT; i += 1024) {
                int ixj = i ^ j;
                if (ixj > i) {
                    unsigned long long a = keys[i], c = keys[ixj];
                    bool up = ((i & k) == 0);
                    if ((a > c) == up) { keys[i] = c; keys[ixj] = a; }
                }
            }
            __syncthreads();
        }
    // first NKK entries = top-k (desc value, asc index on ties)
    if (tid < NKK) idx2[tid] = (unsigned)(keys[tid] & 0xFFFFFFFFu);
    __syncthreads();
    // sort selected indices ascending
    for (int k = 2; k <= NKK; k <<= 1)
        for (int j = k >> 1; j > 0; j >>= 1) {
            if (tid < NKK) {
                int i = tid, ixj = i ^ j;
                if (ixj > i) {
                    unsigned a = idx2[i], c = idx2[ixj];
                    bool up = ((i & k) == 0);
                    if ((a > c) == up) { idx2[i] = c; idx2[ixj] = a; }
                }
            }
            __syncthreads();
        }
    if (tid < NKK) {
        unsigned t = idx2[tid];
        idxv[b * NKK + tid] = (int)t;
        float l = lg[t];
        gates[b * NKK + tid] = 1.f / (1.f + expf(-l));
        atomicAdd(S2, l);
    }
}

__global__ void aux_kernel(const float* S1, const float* S2, float* outp)
{
    outp[0] = (S1[0] - S2[0]) * (0.01f / (float)(NB * NT));
}

// ---------------- gather + rmsnorm ----------------
template<int GATHER>
__global__ __launch_bounds__(256)
void rms_kernel(const float* __restrict__ src, const int* __restrict__ idxv,
                const float* __restrict__ w, float* __restrict__ xsel,
                float* __restrict__ outp)
{
    int blk = blockIdx.x;           // 0..NTOK-1
    int tid = threadIdx.x;          // 256
    const float* x;
    if (GATHER) {
        int b = blk >> 9;
        x = src + ((size_t)b * NT + idxv[blk]) * ND;
    } else {
        x = src + (size_t)blk * ND;
    }
    float4 v = *(const float4*)&x[tid * 4];
    float ss = v.x * v.x + v.y * v.y + v.z * v.z + v.w * v.w;
    for (int off = 32; off; off >>= 1) ss += __shfl_down(ss, off);
    __shared__ float wred[4];
    if ((tid & 63) == 0) wred[tid >> 6] = ss;
    __syncthreads();
    float tot = wred[0] + wred[1] + wred[2] + wred[3];
    float scale = rsqrtf(tot * (1.f / (float)ND) + 1e-6f);
    float4 wv = *(const float4*)&w[tid * 4];
    float4 o;
    o.x = v.x * scale * wv.x; o.y = v.y * scale * wv.y;
    o.z = v.z * scale * wv.z; o.w = v.w * scale * wv.w;
    *(float4*)&outp[(size_t)blk * ND + tid * 4] = o;
    if (GATHER) *(float4*)&xsel[(size_t)blk * ND + tid * 4] = v;
}

// ---------------- simple f32 tiled GEMM, 64x64 tile, 4x4/thread ----------------
// EPI 0: C = acc    EPI 1: C = acc + R    EPI 2: gated scatter epilogue
template<int EPI>
__global__ __launch_bounds__(256)
void sgemm(const float* __restrict__ A, const float* __restrict__ Bm,
           float* __restrict__ C, int M, int N, int K,
           const float* __restrict__ R, const float* __restrict__ xsel,
           const float* __restrict__ gates, const int* __restrict__ idxv,
           float* __restrict__ outp)
{
    __shared__ float As[16][64];
    __shared__ float Bs[16][64];
    int bm = blockIdx.y * 64, bn = blockIdx.x * 64;
    int tid = threadIdx.x;
    int tx = tid & 15, ty = tid >> 4;
    int mA = tid >> 2, kA = (tid & 3) << 2;
    int kB = tid >> 4, nB = (tid & 15) << 2;
    const float* Aptr = A + (size_t)(bm + mA) * K + kA;
    const float* Bptr = Bm + (size_t)kB * N + bn + nB;
    float acc[4][4] = {};
    for (int k0 = 0; k0 < K; k0 += 16) {
        float4 a = *(const float4*)(Aptr + k0);
        float4 bv = *(const float4*)(Bptr + (size_t)k0 * N);
        As[kA + 0][mA] = a.x; As[kA + 1][mA] = a.y;
        As[kA + 2][mA] = a.z; As[kA + 3][mA] = a.w;
        *(float4*)&Bs[kB][nB] = bv;
        __syncthreads();
#pragma unroll
        for (int kk2 = 0; kk2 < 16; ++kk2) {
            float4 av = *(const float4*)&As[kk2][ty << 2];
            float4 bb = *(const float4*)&Bs[kk2][tx << 2];
            float as[4] = {av.x, av.y, av.z, av.w};
            float bs[4] = {bb.x, bb.y, bb.z, bb.w};
#pragma unroll
            for (int i = 0; i < 4; ++i)
#pragma unroll
                for (int j = 0; j < 4; ++j)
                    acc[i][j] = fmaf(as[i], bs[j], acc[i][j]);
        }
        __syncthreads();
    }
#pragma unroll
    for (int i = 0; i < 4; ++i) {
        int row = bm + (ty << 2) + i;
#pragma unroll
        for (int j = 0; j < 4; ++j) {
            int col = bn + (tx << 2) + j;
            float va = acc[i][j];
            if (EPI == 0) {
                C[(size_t)row * N + col] = va;
            } else if (EPI == 1) {
                C[(size_t)row * N + col] = va + R[(size_t)row * N + col];
            } else {
                // va = mlp; block_out = x1 + mlp; new = xs + g*(block_out - xs)
                float xs = xsel[(size_t)row * ND + col];
                float x1v = R[(size_t)row * ND + col];
                float g = gates[row];
                float ns = xs + g * (x1v + va - xs);
                int bb2 = row >> 9;
                int tok = idxv[row];
                outp[((size_t)bb2 * NT + tok) * ND + col] = ns;
            }
        }
    }
}

// ---------------- fused gate/up GEMM with SiLU epilogue ----------------
__global__ __launch_bounds__(256)
void dual_gemm_silu(const float* __restrict__ A, const float* __restrict__ Bg,
                    const float* __restrict__ Bu, float* __restrict__ C,
                    int M, int N, int K)
{
    __shared__ float As[16][64];
    __shared__ float Bsg[16][64];
    __shared__ float Bsu[16][64];
    int bm = blockIdx.y * 64, bn = blockIdx.x * 64;
    int tid = threadIdx.x;
    int tx = tid & 15, ty = tid >> 4;
    int mA = tid >> 2, kA = (tid & 3) << 2;
    int kB = tid >> 4, nB = (tid & 15) << 2;
    const float* Aptr = A + (size_t)(bm + mA) * K + kA;
    const float* Bgp = Bg + (size_t)kB * N + bn + nB;
    const float* Bup = Bu + (size_t)kB * N + bn + nB;
    float accg[4][4] = {};
    float accu[4][4] = {};
    for (int k0 = 0; k0 < K; k0 += 16) {
        float4 a = *(const float4*)(Aptr + k0);
        float4 g4 = *(const float4*)(Bgp + (size_t)k0 * N);
        float4 u4 = *(const float4*)(Bup + (size_t)k0 * N);
        As[kA + 0][mA] = a.x; As[kA + 1][mA] = a.y;
        As[kA + 2][mA] = a.z; As[kA + 3][mA] = a.w;
        *(float4*)&Bsg[kB][nB] = g4;
        *(float4*)&Bsu[kB][nB] = u4;
        __syncthreads();
#pragma unroll
        for (int kk2 = 0; kk2 < 16; ++kk2) {
            float4 av = *(const float4*)&As[kk2][ty << 2];
            float4 bg = *(const float4*)&Bsg[kk2][tx << 2];
            float4 bu = *(const float4*)&Bsu[kk2][tx << 2];
            float as[4] = {av.x, av.y, av.z, av.w};
            float gs[4] = {bg.x, bg.y, bg.z, bg.w};
            float us[4] = {bu.x, bu.y, bu.z, bu.w};
#pragma unroll
            for (int i = 0; i < 4; ++i)
#pragma unroll
                for (int j = 0; j < 4; ++j) {
                    accg[i][j] = fmaf(as[i], gs[j], accg[i][j]);
                    accu[i][j] = fmaf(as[i], us[j], accu[i][j]);
                }
        }
        __syncthreads();
    }
#pragma unroll
    for (int i = 0; i < 4; ++i) {
        int row = bm + (ty << 2) + i;
#pragma unroll
        for (int j = 0; j < 4; ++j) {
            int col = bn + (tx << 2) + j;
            float g = accg[i][j];
            float act = (g / (1.f + expf(-g))) * accu[i][j];
            C[(size_t)row * N + col] = act;
        }
    }
}

// ---------------- RoPE on q and k (in-place) ----------------
__global__ __launch_bounds__(256)
void rope_kernel(float* __restrict__ qb, float* __restrict__ kb,
                 const int* __restrict__ idxv)
{
    int row = blockIdx.x;                 // 0..NTOK-1
    float* ptr = blockIdx.y ? kb : qb;
    float pos = (float)idxv[row];
    int tid = threadIdx.x;
    for (int p = tid; p < NH * 32; p += 256) {
        int h = p >> 5, j = p & 31;
        float inv = powf(10000.f, -(float)j * (1.f / 32.f));
        float ang = pos * inv;
        float s = sinf(ang), c = cosf(ang);
        size_t base = (size_t)row * ND + h * NDH + j;
        float x1 = ptr[base], x2 = ptr[base + 32];
        ptr[base] = x1 * c - x2 * s;
        ptr[base + 32] = x2 * c + x1 * s;
    }
}

// ---------------- causal attention over selected tokens ----------------
__global__ __launch_bounds__(256)
void attn_kernel(const float* __restrict__ q, const float* __restrict__ k,
                 const float* __restrict__ v, float* __restrict__ ao)
{
    __shared__ float p[4][NKK];
    int wave = threadIdx.x >> 6, lane = threadIdx.x & 63;
    int w = blockIdx.x * 4 + wave;        // 0..NB*NH*NKK-1
    int qi = w & (NKK - 1);
    int bh = w >> 9;                      // 0..63
    int b = bh >> 4, h = bh & 15;
    size_t rowbase = (size_t)(b * NKK) * ND + h * NDH;
    float qd = q[rowbase + (size_t)qi * ND + lane];
    float* pw = p[wave];
    const float* kbase = k + rowbase;
    float mx = -1e30f;
    for (int j = 0; j <= qi; ++j) {
        float prod = qd * kbase[(size_t)j * ND + lane];
        for (int off = 32; off; off >>= 1) prod += __shfl_down(prod, off);
        prod = __shfl(prod, 0) * 0.125f;   // 1/sqrt(64)
        if (lane == 0) pw[j] = prod;
        mx = fmaxf(mx, prod);
    }
    float sum = 0.f;
    for (int j = lane; j <= qi; j += 64) {
        float e = expf(pw[j] - mx);
        pw[j] = e;
        sum += e;
    }
    for (int off = 32; off; off >>= 1) sum += __shfl_down(sum, off);
    sum = __shfl(sum, 0);
    float inv = 1.f / sum;
    const float* vbase = v + rowbase;
    float od = 0.f;
    for (int j = 0; j <= qi; ++j) od += pw[j] * vbase[(size_t)j * ND + lane];
    ao[rowbase + (size_t)qi * ND + lane] = od * inv;
}

extern "C" void kernel_launch(void* const* d_in, const int* in_sizes, int n_in,
                              void* d_out, int out_size, void* d_ws, size_t ws_size,
                              hipStream_t stream)
{
    const float* hs  = (const float*)d_in[0];
    const float* wr  = (const float*)d_in[1];
    const float* wq  = (const float*)d_in[2];
    const float* wk  = (const float*)d_in[3];
    const float* wv  = (const float*)d_in[4];
    const float* wo  = (const float*)d_in[5];
    const float* ln1 = (const float*)d_in[6];
    const float* ln2 = (const float*)d_in[7];
    const float* wg  = (const float*)d_in[8];
    const float* wu  = (const float*)d_in[9];
    const float* wd  = (const float*)d_in[10];
    float* out = (float*)d_out;
    float* ws  = (float*)d_ws;

    // workspace layout (floats); total ~21.0M floats ~84 MB
    float* logits = ws;                       // 16384
    float* S1     = ws + 16384;
    float* S2     = ws + 16385;
    int*   idxv   = (int*)(ws + 17408);       // 2048
    float* gates  = ws + 19456;               // 2048
    float* xsel   = ws + 21504;               // 2M
    float* hbuf   = xsel + (size_t)NTOK * ND; // 2M (reused as h2)
    float* qb     = hbuf + (size_t)NTOK * ND; // 2M (reused as x1)
    float* kb     = qb   + (size_t)NTOK * ND;
    float* vb     = kb   + (size_t)NTOK * ND;
    float* aob    = vb   + (size_t)NTOK * ND;
    float* actb   = aob  + (size_t)NTOK * ND; // 8M
    float* x1b = qb;
    float* h2b = hbuf;

    // base output = input hidden states; selected rows overwritten later
    hipMemcpyAsync(out, hs, OUT_MAIN * sizeof(float),
                   hipMemcpyDeviceToDevice, stream);
    hipMemsetAsync(S1, 0, 2 * sizeof(float), stream);

    router_kernel<<<NB * NT / 4, 256, 0, stream>>>(hs, wr, logits, S1);
    topk_kernel<<<NB, 1024, 0, stream>>>(logits, idxv, gates, S2);
    aux_kernel<<<1, 1, 0, stream>>>(S1, S2, out + OUT_MAIN);

    rms_kernel<1><<<NTOK, 256, 0, stream>>>(hs, idxv, ln1, xsel, hbuf);

    sgemm<0><<<dim3(ND / 64, NTOK / 64), 256, 0, stream>>>(
        hbuf, wq, qb, NTOK, ND, ND, nullptr, nullptr, nullptr, nullptr, nullptr);
    sgemm<0><<<dim3(ND / 64, NTOK / 64), 256, 0, stream>>>(
        hbuf, wk, kb, NTOK, ND, ND, nullptr, nullptr, nullptr, nullptr, nullptr);
    sgemm<0><<<dim3(ND / 64, NTOK / 64), 256, 0, stream>>>(
        hbuf, wv, vb, NTOK, ND, ND, nullptr, nullptr, nullptr, nullptr, nullptr);

    rope_kernel<<<dim3(NTOK, 2), 256, 0, stream>>>(qb, kb, idxv);

    attn_kernel<<<NB * NH * NKK / 4, 256, 0, stream>>>(qb, kb, vb, aob);

    // x1 = ao @ wo + x_sel (x1 aliases qb)
    sgemm<1><<<dim3(ND / 64, NTOK / 64), 256, 0, stream>>>(
        aob, wo, x1b, NTOK, ND, ND, xsel, nullptr, nullptr, nullptr, nullptr);

    rms_kernel<0><<<NTOK, 256, 0, stream>>>(x1b, idxv, ln2, nullptr, h2b);

    dual_gemm_silu<<<dim3(NFF / 64, NTOK / 64), 256, 0, stream>>>(
        h2b, wg, wu, actb, NTOK, NFF, ND);

    // mlp = act @ wd; fused: block_out, gated update, scatter into out
    sgemm<2><<<dim3(ND / 64, NTOK / 64), 256, 0, stream>>>(
        actb, wd, nullptr, NTOK, ND, NFF, x1b, xsel, gates, idxv, out);
}

// Round 3
// 725.531 us; speedup vs baseline: 3.3084x; 3.3084x over previous
//
#include <hip/hip_runtime.h>
#include <math.h>

#define NB 4
#define NT 4096
#define ND 1024
#define NH 16
#define NDH 64
#define NFF 4096
#define NKK 512
#define NTOK (NB*NKK)                 // 2048
#define OUT_MAIN ((size_t)NB*NT*ND)   // 16777216

typedef unsigned short u16;
typedef __bf16 bf16x8 __attribute__((ext_vector_type(8)));
typedef short  s16x8  __attribute__((ext_vector_type(8)));
typedef unsigned short u16x4 __attribute__((ext_vector_type(4)));
typedef float  f32x4  __attribute__((ext_vector_type(4)));

__device__ inline u16 f2b(float f) {
    unsigned u = __builtin_bit_cast(unsigned, f);
    unsigned r = u + 0x7FFFu + ((u >> 16) & 1u);
    return (u16)(r >> 16);
}
__device__ inline float b2f(u16 v) {
    unsigned u = ((unsigned)v) << 16;
    return __builtin_bit_cast(float, u);
}

// ---------------- router: logits + softplus partial sum ----------------
__global__ __launch_bounds__(256)
void router_kernel(const float* __restrict__ hs, const float* __restrict__ wr,
                   float* __restrict__ logits, float* __restrict__ S1)
{
    int wave = threadIdx.x >> 6, lane = threadIdx.x & 63;
    int row = blockIdx.x * 4 + wave;
    const float4* x4 = (const float4*)(hs + (size_t)row * ND);
    const float4* w4 = (const float4*)wr;
    float acc = 0.f;
#pragma unroll
    for (int i = 0; i < 4; ++i) {
        float4 a = x4[lane + i * 64];
        float4 b = w4[lane + i * 64];
        acc += a.x * b.x + a.y * b.y + a.z * b.z + a.w * b.w;
    }
    for (int off = 32; off; off >>= 1) acc += __shfl_down(acc, off);
    if (lane == 0) {
        logits[row] = acc;
        float sp = fmaxf(acc, 0.f) + log1pf(expf(-fabsf(acc)));
        atomicAdd(S1, sp);
    }
}

// ---------------- per-batch top-k via bitonic sort ----------------
__global__ __launch_bounds__(1024)
void topk_kernel(const float* __restrict__ logits, int* __restrict__ idxv,
                 float* __restrict__ gates, float* __restrict__ S2)
{
    __shared__ unsigned long long keys[NT];
    __shared__ unsigned idx2[NKK];
    int b = blockIdx.x, tid = threadIdx.x;
    const float* lg = logits + (size_t)b * NT;
    for (int i = tid; i < NT; i += 1024) {
        unsigned u = __float_as_uint(lg[i]);
        u ^= (u >> 31) ? 0xFFFFFFFFu : 0x80000000u;
        u = ~u;
        keys[i] = ((unsigned long long)u << 32) | (unsigned)i;
    }
    __syncthreads();
    for (int k = 2; k <= NT; k <<= 1)
        for (int j = k >> 1; j > 0; j >>= 1) {
            for (int i = tid; i < NT; i += 1024) {
                int ixj = i ^ j;
                if (ixj > i) {
                    unsigned long long a = keys[i], c = keys[ixj];
                    bool up = ((i & k) == 0);
                    if ((a > c) == up) { keys[i] = c; keys[ixj] = a; }
                }
            }
            __syncthreads();
        }
    if (tid < NKK) idx2[tid] = (unsigned)(keys[tid] & 0xFFFFFFFFu);
    __syncthreads();
    for (int k = 2; k <= NKK; k <<= 1)
        for (int j = k >> 1; j > 0; j >>= 1) {
            if (tid < NKK) {
                int i = tid, ixj = i ^ j;
                if (ixj > i) {
                    unsigned a = idx2[i], c = idx2[ixj];
                    bool up = ((i & k) == 0);
                    if ((a > c) == up) { idx2[i] = c; idx2[ixj] = a; }
                }
            }
            __syncthreads();
        }
    if (tid < NKK) {
        unsigned t = idx2[tid];
        idxv[b * NKK + tid] = (int)t;
        float l = lg[t];
        gates[b * NKK + tid] = 1.f / (1.f + expf(-l));
        atomicAdd(S2, l);
    }
}

__global__ void aux_kernel(const float* S1, const float* S2, float* outp)
{
    outp[0] = (S1[0] - S2[0]) * (0.01f / (float)(NB * NT));
}

// ---------------- weight transpose + bf16 convert: dst[N][K] = src[K][N] ----------------
__global__ __launch_bounds__(256)
void transpose_conv(const float* __restrict__ src, u16* __restrict__ dst,
                    int K, int N)
{
    __shared__ u16 T[64][68];
    int n0 = blockIdx.x * 64, k0 = blockIdx.y * 64;
    int tid = threadIdx.x;
#pragma unroll
    for (int it = 0; it < 4; ++it) {
        int slot = it * 256 + tid;
        int k = slot >> 4, n4 = (slot & 15) * 4;
        float4 v = *(const float4*)&src[(size_t)(k0 + k) * N + n0 + n4];
        u16x4 o = { f2b(v.x), f2b(v.y), f2b(v.z), f2b(v.w) };
        *(u16x4*)&T[k][n4] = o;
    }
    __syncthreads();
#pragma unroll
    for (int it = 0; it < 2; ++it) {
        int slot = it * 256 + tid;
        int n = slot >> 3, k8 = (slot & 7) * 8;
        s16x8 o;
#pragma unroll
        for (int i = 0; i < 8; ++i) o[i] = (short)T[k8 + i][n];
        *(s16x8*)&dst[(size_t)(n0 + n) * K + k0 + k8] = o;
    }
}

// ---------------- gather + rmsnorm (f32 in, bf16 out) ----------------
template<int GATHER>
__global__ __launch_bounds__(256)
void rms_kernel(const float* __restrict__ src, const int* __restrict__ idxv,
                const float* __restrict__ w, float* __restrict__ xsel,
                u16* __restrict__ outp)
{
    int blk = blockIdx.x, tid = threadIdx.x;
    const float* x;
    if (GATHER) {
        int b = blk >> 9;
        x = src + ((size_t)b * NT + idxv[blk]) * ND;
    } else {
        x = src + (size_t)blk * ND;
    }
    float4 v = *(const float4*)&x[tid * 4];
    float ss = v.x * v.x + v.y * v.y + v.z * v.z + v.w * v.w;
    for (int off = 32; off; off >>= 1) ss += __shfl_down(ss, off);
    __shared__ float wred[4];
    if ((tid & 63) == 0) wred[tid >> 6] = ss;
    __syncthreads();
    float tot = wred[0] + wred[1] + wred[2] + wred[3];
    float scale = rsqrtf(tot * (1.f / (float)ND) + 1e-6f);
    float4 wv = *(const float4*)&w[tid * 4];
    u16x4 o = { f2b(v.x * scale * wv.x), f2b(v.y * scale * wv.y),
                f2b(v.z * scale * wv.z), f2b(v.w * scale * wv.w) };
    *(u16x4*)&outp[(size_t)blk * ND + tid * 4] = o;
    if (GATHER) *(float4*)&xsel[(size_t)blk * ND + tid * 4] = v;
}

// ---------------- bf16 MFMA GEMM: C[M][N] = A[M][K] * B^T  (B given as [N][K]) ----
// EPI 1: C bf16   EPI 2: C f32 = acc + P1   EPI 3: gated scatter to outp
#define LPAD 40
template<int EPI>
__global__ __launch_bounds__(256)
void gemm_bt(const u16* __restrict__ A, const u16* __restrict__ B,
             void* __restrict__ Cv, int K, int lda, int ldb, int ldc,
             const float* __restrict__ P1, const float* __restrict__ P2,
             const float* __restrict__ gates, const int* __restrict__ idxv,
             float* __restrict__ outp)
{
    __shared__ u16 As[128 * LPAD];
    __shared__ u16 Bs[128 * LPAD];
    int tid = threadIdx.x, lane = tid & 63, w = tid >> 6;
    int wr = w >> 1, wc = w & 1;
    int bm = blockIdx.y * 128, bn = blockIdx.x * 128;
    int arow = tid >> 2, acol = (tid & 3) * 8;
    const u16* Ap = A + (size_t)(bm + arow) * lda + acol;
    const u16* Ap2 = Ap + (size_t)64 * lda;
    const u16* Bp = B + (size_t)(bn + arow) * ldb + acol;
    const u16* Bp2 = Bp + (size_t)64 * ldb;
    int c15 = lane & 15, ks8 = (lane >> 4) * 8;
    int aoff[4], boff[4];
#pragma unroll
    for (int m2 = 0; m2 < 4; ++m2) aoff[m2] = (wr * 64 + m2 * 16 + c15) * LPAD + ks8;
#pragma unroll
    for (int n2 = 0; n2 < 4; ++n2) boff[n2] = (wc * 64 + n2 * 16 + c15) * LPAD + ks8;
    f32x4 acc[4][4] = {};
    for (int k0 = 0; k0 < K; k0 += 32) {
        s16x8 a0 = *(const s16x8*)(Ap + k0);
        s16x8 a1 = *(const s16x8*)(Ap2 + k0);
        s16x8 b0 = *(const s16x8*)(Bp + k0);
        s16x8 b1 = *(const s16x8*)(Bp2 + k0);
        __syncthreads();
        *(s16x8*)&As[arow * LPAD + acol] = a0;
        *(s16x8*)&As[(arow + 64) * LPAD + acol] = a1;
        *(s16x8*)&Bs[arow * LPAD + acol] = b0;
        *(s16x8*)&Bs[(arow + 64) * LPAD + acol] = b1;
        __syncthreads();
        bf16x8 af[4], bfr[4];
#pragma unroll
        for (int m2 = 0; m2 < 4; ++m2) af[m2] = *(const bf16x8*)&As[aoff[m2]];
#pragma unroll
        for (int n2 = 0; n2 < 4; ++n2) bfr[n2] = *(const bf16x8*)&Bs[boff[n2]];
#pragma unroll
        for (int m2 = 0; m2 < 4; ++m2)
#pragma unroll
            for (int n2 = 0; n2 < 4; ++n2)
                acc[m2][n2] = __builtin_amdgcn_mfma_f32_16x16x32_bf16(
                    af[m2], bfr[n2], acc[m2][n2], 0, 0, 0);
    }
    int r4 = (lane >> 4) * 4;
#pragma unroll
    for (int m2 = 0; m2 < 4; ++m2) {
#pragma unroll
        for (int n2 = 0; n2 < 4; ++n2) {
            f32x4 v = acc[m2][n2];
            int c = bn + wc * 64 + n2 * 16 + c15;
            int r0 = bm + wr * 64 + m2 * 16 + r4;
#pragma unroll
            for (int j = 0; j < 4; ++j) {
                int r = r0 + j;
                float val = v[j];
                if (EPI == 1) {
                    ((u16*)Cv)[(size_t)r * ldc + c] = f2b(val);
                } else if (EPI == 2) {
                    ((float*)Cv)[(size_t)r * ldc + c] = val + P1[(size_t)r * ldc + c];
                } else {
                    float x1v = P1[(size_t)r * ND + c];
                    float xs  = P2[(size_t)r * ND + c];
                    float g = gates[r];
                    float ns = xs + g * (x1v + val - xs);
                    int bb = r >> 9;
                    int tok = idxv[r];
                    outp[((size_t)bb * NT + tok) * ND + c] = ns;
                }
            }
        }
    }
}

// ---------------- RoPE on bf16 q,k (cols 0..2047 of qkv), in place ----------------
__global__ __launch_bounds__(256)
void rope_kernel(u16* __restrict__ qkv, const int* __restrict__ idxv)
{
    int row = blockIdx.x;
    float pos = (float)idxv[row];
    int tid = threadIdx.x;
    for (int p = tid; p < 1024; p += 256) {
        int sec = p >> 9, h = (p >> 5) & 15, j = p & 31;
        float inv = expf(-(float)j * 0.28782313662f);   // ln(10000)/32
        float ang = pos * inv;
        float s = sinf(ang), c = cosf(ang);
        size_t base = (size_t)row * 3072 + sec * 1024 + h * 64 + j;
        float x1 = b2f(qkv[base]), x2 = b2f(qkv[base + 32]);
        qkv[base] = f2b(x1 * c - x2 * s);
        qkv[base + 32] = f2b(x2 * c + x1 * s);
    }
}

// ---------------- flash attention (bf16 MFMA, online softmax) ----------------
__global__ __launch_bounds__(256)
void flash_attn(const u16* __restrict__ qkv, u16* __restrict__ ao)
{
    __shared__ u16 Qs[128 * 72];
    __shared__ u16 Ks[64 * 72];
    __shared__ u16 Vt[64 * 72];
    __shared__ u16 Ps[128 * 72];
    int qt = blockIdx.x, h = blockIdx.y, b = blockIdx.z;
    int tid = threadIdx.x, lane = tid & 63, w = tid >> 6;
    size_t rowbase = (size_t)b * NKK;
    int c15 = lane & 15, ks8 = (lane >> 4) * 8, r4 = (lane >> 4) * 4;
    // stage Q tile (rows qt*128..+127, head h)
#pragma unroll
    for (int it = 0; it < 4; ++it) {
        int slot = it * 256 + tid;
        int r = slot >> 3, c8 = (slot & 7) * 8;
        s16x8 qv = *(const s16x8*)&qkv[(rowbase + qt * 128 + r) * 3072 + h * 64 + c8];
        *(s16x8*)&Qs[r * 72 + c8] = qv;
    }
    float m_run[2][4], l_run[2][4];
#pragma unroll
    for (int m2 = 0; m2 < 2; ++m2)
#pragma unroll
        for (int j = 0; j < 4; ++j) { m_run[m2][j] = -1e30f; l_run[m2][j] = 0.f; }
    f32x4 oacc[2][4] = {};
    int q0w = qt * 128 + w * 32;
    int nkt = (qt + 1) * 2;
    for (int kt = 0; kt < nkt; ++kt) {
        __syncthreads();
#pragma unroll
        for (int it = 0; it < 2; ++it) {
            int slot = it * 256 + tid;
            int r = slot >> 3, c8 = (slot & 7) * 8;
            s16x8 kv_ = *(const s16x8*)&qkv[(rowbase + kt * 64 + r) * 3072 + 1024 + h * 64 + c8];
            *(s16x8*)&Ks[r * 72 + c8] = kv_;
        }
#pragma unroll
        for (int it = 0; it < 2; ++it) {
            int slot = it * 256 + tid;
            int r = slot >> 3, c8 = (slot & 7) * 8;
            s16x8 vv = *(const s16x8*)&qkv[(rowbase + kt * 64 + r) * 3072 + 2048 + h * 64 + c8];
#pragma unroll
            for (int i = 0; i < 8; ++i) Vt[(c8 + i) * 72 + r] = (u16)vv[i];
        }
        __syncthreads();
        if (kt * 64 <= q0w + 31) {
            // S = Q K^T
            f32x4 sacc[2][4] = {};
#pragma unroll
            for (int ks = 0; ks < 2; ++ks) {
                bf16x8 af[2], bfr[4];
#pragma unroll
                for (int m2 = 0; m2 < 2; ++m2)
                    af[m2] = *(const bf16x8*)&Qs[(w * 32 + m2 * 16 + c15) * 72 + ks * 32 + ks8];
#pragma unroll
                for (int n2 = 0; n2 < 4; ++n2)
                    bfr[n2] = *(const bf16x8*)&Ks[(n2 * 16 + c15) * 72 + ks * 32 + ks8];
#pragma unroll
                for (int m2 = 0; m2 < 2; ++m2)
#pragma unroll
                    for (int n2 = 0; n2 < 4; ++n2)
                        sacc[m2][n2] = __builtin_amdgcn_mfma_f32_16x16x32_bf16(
                            af[m2], bfr[n2], sacc[m2][n2], 0, 0, 0);
            }
            // mask + online softmax + write P
#pragma unroll
            for (int m2 = 0; m2 < 2; ++m2) {
#pragma unroll
                for (int j = 0; j < 4; ++j) {
                    int rowv = q0w + m2 * 16 + r4 + j;
                    float sv[4];
#pragma unroll
                    for (int n2 = 0; n2 < 4; ++n2) {
                        int colv = kt * 64 + n2 * 16 + c15;
                        float s = sacc[m2][n2][j] * 0.125f;
                        sv[n2] = (colv > rowv) ? -1e30f : s;
                    }
                    float mx = fmaxf(fmaxf(sv[0], sv[1]), fmaxf(sv[2], sv[3]));
                    mx = fmaxf(mx, __shfl_xor(mx, 1));
                    mx = fmaxf(mx, __shfl_xor(mx, 2));
                    mx = fmaxf(mx, __shfl_xor(mx, 4));
                    mx = fmaxf(mx, __shfl_xor(mx, 8));
                    float newm = fmaxf(m_run[m2][j], mx);
                    float alpha = __expf(m_run[m2][j] - newm);
                    m_run[m2][j] = newm;
                    float ls = 0.f;
                    int prow = w * 32 + m2 * 16 + r4 + j;
#pragma unroll
                    for (int n2 = 0; n2 < 4; ++n2) {
                        float pexp = __expf(sv[n2] - newm);
                        ls += pexp;
                        Ps[prow * 72 + n2 * 16 + c15] = f2b(pexp);
                    }
                    ls += __shfl_xor(ls, 1);
                    ls += __shfl_xor(ls, 2);
                    ls += __shfl_xor(ls, 4);
                    ls += __shfl_xor(ls, 8);
                    l_run[m2][j] = l_run[m2][j] * alpha + ls;
#pragma unroll
                    for (int n2 = 0; n2 < 4; ++n2) oacc[m2][n2][j] *= alpha;
                }
            }
            // O += P V
#pragma unroll
            for (int ks = 0; ks < 2; ++ks) {
                bf16x8 pa[2], vb[4];
#pragma unroll
                for (int m2 = 0; m2 < 2; ++m2)
                    pa[m2] = *(const bf16x8*)&Ps[(w * 32 + m2 * 16 + c15) * 72 + ks * 32 + ks8];
#pragma unroll
                for (int n2 = 0; n2 < 4; ++n2)
                    vb[n2] = *(const bf16x8*)&Vt[(n2 * 16 + c15) * 72 + ks * 32 + ks8];
#pragma unroll
                for (int m2 = 0; m2 < 2; ++m2)
#pragma unroll
                    for (int n2 = 0; n2 < 4; ++n2)
                        oacc[m2][n2] = __builtin_amdgcn_mfma_f32_16x16x32_bf16(
                            pa[m2], vb[n2], oacc[m2][n2], 0, 0, 0);
            }
        }
    }
    // epilogue: ao = O / l
#pragma unroll
    for (int m2 = 0; m2 < 2; ++m2) {
#pragma unroll
        for (int j = 0; j < 4; ++j) {
            float invl = 1.f / l_run[m2][j];
            size_t r = rowbase + q0w + m2 * 16 + r4 + j;
#pragma unroll
            for (int n2 = 0; n2 < 4; ++n2)
                ao[r * ND + h * 64 + n2 * 16 + c15] = f2b(oacc[m2][n2][j] * invl);
        }
    }
}

// ---------------- dual GEMM gate/up with fused SiLU (bf16 MFMA) ----------------
__global__ __launch_bounds__(256)
void dual_gemm_silu(const u16* __restrict__ A, const u16* __restrict__ Bw,
                    u16* __restrict__ act)
{
    __shared__ u16 As[128 * LPAD];
    __shared__ u16 Bg[64 * LPAD];
    __shared__ u16 Bu[64 * LPAD];
    int tid = threadIdx.x, lane = tid & 63, w = tid >> 6;
    int bm = blockIdx.y * 128, bn = blockIdx.x * 64;
    int arow = tid >> 2, acol = (tid & 3) * 8;
    const u16* Ap = A + (size_t)(bm + arow) * ND + acol;
    const u16* Ap2 = Ap + (size_t)64 * ND;
    const u16* Gp = Bw + (size_t)(bn + arow) * ND + acol;
    const u16* Up = Bw + (size_t)(NFF + bn + arow) * ND + acol;
    int c15 = lane & 15, ks8 = (lane >> 4) * 8;
    int aoff[2], boff[4];
#pragma unroll
    for (int m2 = 0; m2 < 2; ++m2) aoff[m2] = (w * 32 + m2 * 16 + c15) * LPAD + ks8;
#pragma unroll
    for (int n2 = 0; n2 < 4; ++n2) boff[n2] = (n2 * 16 + c15) * LPAD + ks8;
    f32x4 accg[2][4] = {}, accu[2][4] = {};
    for (int k0 = 0; k0 < ND; k0 += 32) {
        s16x8 a0 = *(const s16x8*)(Ap + k0);
        s16x8 a1 = *(const s16x8*)(Ap2 + k0);
        s16x8 g0 = *(const s16x8*)(Gp + k0);
        s16x8 u0 = *(const s16x8*)(Up + k0);
        __syncthreads();
        *(s16x8*)&As[arow * LPAD + acol] = a0;
        *(s16x8*)&As[(arow + 64) * LPAD + acol] = a1;
        *(s16x8*)&Bg[arow * LPAD + acol] = g0;
        *(s16x8*)&Bu[arow * LPAD + acol] = u0;
        __syncthreads();
        bf16x8 af[2], gf[4], uf[4];
#pragma unroll
        for (int m2 = 0; m2 < 2; ++m2) af[m2] = *(const bf16x8*)&As[aoff[m2]];
#pragma unroll
        for (int n2 = 0; n2 < 4; ++n2) { gf[n2] = *(const bf16x8*)&Bg[boff[n2]];
                                         uf[n2] = *(const bf16x8*)&Bu[boff[n2]]; }
#pragma unroll
        for (int m2 = 0; m2 < 2; ++m2)
#pragma unroll
            for (int n2 = 0; n2 < 4; ++n2) {
                accg[m2][n2] = __builtin_amdgcn_mfma_f32_16x16x32_bf16(
                    af[m2], gf[n2], accg[m2][n2], 0, 0, 0);
                accu[m2][n2] = __builtin_amdgcn_mfma_f32_16x16x32_bf16(
                    af[m2], uf[n2], accu[m2][n2], 0, 0, 0);
            }
    }
    int r4 = (lane >> 4) * 4;
#pragma unroll
    for (int m2 = 0; m2 < 2; ++m2)
#pragma unroll
        for (int n2 = 0; n2 < 4; ++n2)
#pragma unroll
            for (int j = 0; j < 4; ++j) {
                float g = accg[m2][n2][j], uu = accu[m2][n2][j];
                float a = g / (1.f + __expf(-g)) * uu;
                int r = bm + w * 32 + m2 * 16 + r4 + j;
                int c = bn + n2 * 16 + c15;
                act[(size_t)r * NFF + c] = f2b(a);
            }
}

extern "C" void kernel_launch(void* const* d_in, const int* in_sizes, int n_in,
                              void* d_out, int out_size, void* d_ws, size_t ws_size,
                              hipStream_t stream)
{
    const float* hs  = (const float*)d_in[0];
    const float* wr  = (const float*)d_in[1];
    const float* wq  = (const float*)d_in[2];
    const float* wk  = (const float*)d_in[3];
    const float* wv  = (const float*)d_in[4];
    const float* wo  = (const float*)d_in[5];
    const float* ln1 = (const float*)d_in[6];
    const float* ln2 = (const float*)d_in[7];
    const float* wg  = (const float*)d_in[8];
    const float* wu  = (const float*)d_in[9];
    const float* wd  = (const float*)d_in[10];
    float* out = (float*)d_out;
    char* w8 = (char*)d_ws;

    // ---- workspace layout (~76 MB) ----
    float* logits = (float*)w8;                       // 64 KB
    float* S1 = logits + 16384;
    float* S2 = S1 + 1;
    int*   idxv  = (int*)(w8 + 0x20000);              // 8 KB
    float* gates = (float*)(w8 + 0x22000);            // 8 KB
    float* xsel  = (float*)(w8 + 0x30000);            // 8 MB
    float* x1b   = xsel + (size_t)NTOK * ND;          // 8 MB
    u16*   hbuf  = (u16*)(x1b + (size_t)NTOK * ND);   // 4 MB (h, then h2)
    u16*   wqkvT = hbuf + (size_t)NTOK * ND;          // 6 MB
    u16*   woT   = wqkvT + (size_t)3072 * 1024;       // 2 MB
    u16*   wguT  = woT + (size_t)1024 * 1024;         // 16 MB
    u16*   wdT   = wguT + (size_t)8192 * 1024;        // 8 MB
    u16*   act   = wdT + (size_t)1024 * 4096;         // 16 MB
    u16*   qkv   = act + (size_t)NTOK * NFF;          // 12 MB
    u16*   ao    = qkv + (size_t)NTOK * 3072;         // 4 MB

    hipMemcpyAsync(out, hs, OUT_MAIN * sizeof(float), hipMemcpyDeviceToDevice, stream);
    hipMemsetAsync(S1, 0, 2 * sizeof(float), stream);

    // weight prep (transpose + bf16)
    transpose_conv<<<dim3(16, 16), 256, 0, stream>>>(wq, wqkvT, 1024, 1024);
    transpose_conv<<<dim3(16, 16), 256, 0, stream>>>(wk, wqkvT + (size_t)1024 * 1024, 1024, 1024);
    transpose_conv<<<dim3(16, 16), 256, 0, stream>>>(wv, wqkvT + (size_t)2048 * 1024, 1024, 1024);
    transpose_conv<<<dim3(16, 16), 256, 0, stream>>>(wo, woT, 1024, 1024);
    transpose_conv<<<dim3(64, 16), 256, 0, stream>>>(wg, wguT, 1024, 4096);
    transpose_conv<<<dim3(64, 16), 256, 0, stream>>>(wu, wguT + (size_t)4096 * 1024, 1024, 4096);
    transpose_conv<<<dim3(16, 64), 256, 0, stream>>>(wd, wdT, 4096, 1024);

    router_kernel<<<NB * NT / 4, 256, 0, stream>>>(hs, wr, logits, S1);
    topk_kernel<<<NB, 1024, 0, stream>>>(logits, idxv, gates, S2);
    aux_kernel<<<1, 1, 0, stream>>>(S1, S2, out + OUT_MAIN);

    rms_kernel<1><<<NTOK, 256, 0, stream>>>(hs, idxv, ln1, xsel, hbuf);

    // QKV: [2048,1024] x [1024,3072] -> qkv bf16 [2048][3072]
    gemm_bt<1><<<dim3(24, 16), 256, 0, stream>>>(
        hbuf, wqkvT, qkv, 1024, 1024, 1024, 3072,
        nullptr, nullptr, nullptr, nullptr, nullptr);

    rope_kernel<<<NTOK, 256, 0, stream>>>(qkv, idxv);

    flash_attn<<<dim3(4, NH, NB), 256, 0, stream>>>(qkv, ao);

    // x1 = ao @ wo + xsel  (f32)
    gemm_bt<2><<<dim3(8, 16), 256, 0, stream>>>(
        ao, woT, x1b, 1024, 1024, 1024, 1024,
        xsel, nullptr, nullptr, nullptr, nullptr);

    rms_kernel<0><<<NTOK, 256, 0, stream>>>(x1b, idxv, ln2, nullptr, hbuf);

    // act = silu(h2 @ wg) * (h2 @ wu)  bf16 [2048][4096]
    dual_gemm_silu<<<dim3(64, 16), 256, 0, stream>>>(hbuf, wguT, act);

    // mlp = act @ wd; fused gated scatter into out
    gemm_bt<3><<<dim3(8, 16), 256, 0, stream>>>(
        act, wdT, nullptr, 4096, 4096, 4096, 1024,
        x1b, xsel, gates, idxv, out);
}

// Round 4
// 513.370 us; speedup vs baseline: 4.6756x; 1.4133x over previous
//
#include <hip/hip_runtime.h>
#include <math.h>

#define NB 4
#define NT 4096
#define ND 1024
#define NH 16
#define NDH 64
#define NFF 4096
#define NKK 512
#define NTOK (NB*NKK)                 // 2048
#define OUT_MAIN ((size_t)NB*NT*ND)   // 16777216

typedef unsigned short u16;
typedef __bf16 bf16x8 __attribute__((ext_vector_type(8)));
typedef short  s16x8  __attribute__((ext_vector_type(8)));
typedef unsigned short u16x4 __attribute__((ext_vector_type(4)));
typedef float  f32x4  __attribute__((ext_vector_type(4)));

__device__ inline u16 f2b(float f) {
    unsigned u = __builtin_bit_cast(unsigned, f);
    unsigned r = u + 0x7FFFu + ((u >> 16) & 1u);
    return (u16)(r >> 16);
}
__device__ inline float b2f(u16 v) {
    unsigned u = ((unsigned)v) << 16;
    return __builtin_bit_cast(float, u);
}

// ---------------- router: logits + per-block softplus partial ----------------
__global__ __launch_bounds__(256)
void router_kernel(const float* __restrict__ hs, const float* __restrict__ wr,
                   float* __restrict__ logits, float* __restrict__ partials)
{
    int wave = threadIdx.x >> 6, lane = threadIdx.x & 63;
    int row = blockIdx.x * 4 + wave;
    const float4* x4 = (const float4*)(hs + (size_t)row * ND);
    const float4* w4 = (const float4*)wr;
    float acc = 0.f;
#pragma unroll
    for (int i = 0; i < 4; ++i) {
        float4 a = x4[lane + i * 64];
        float4 b = w4[lane + i * 64];
        acc += a.x * b.x + a.y * b.y + a.z * b.z + a.w * b.w;
    }
    for (int off = 32; off; off >>= 1) acc += __shfl_down(acc, off);
    __shared__ float sp4[4];
    if (lane == 0) {
        logits[row] = acc;
        sp4[wave] = fmaxf(acc, 0.f) + log1pf(expf(-fabsf(acc)));
    }
    __syncthreads();
    if (threadIdx.x == 0)
        partials[blockIdx.x] = sp4[0] + sp4[1] + sp4[2] + sp4[3];
}

// ---------------- per-batch exact top-k via radix select + compaction ----------------
__global__ __launch_bounds__(1024)
void topk_kernel(const float* __restrict__ logits, int* __restrict__ idxv,
                 float* __restrict__ gates, float* __restrict__ S2)
{
    __shared__ unsigned key[NT];          // 16 KB sortable keys
    __shared__ unsigned hist[256];
    __shared__ unsigned wsum[16];
    __shared__ float red[16];
    __shared__ unsigned sh_pref, sh_r;
    int b = blockIdx.x, tid = threadIdx.x;
    int lane = tid & 63, wv = tid >> 6;   // 16 waves
    const float* lg = logits + (size_t)b * NT;
    // sortable key: ascending key order == ascending float order
    for (int i = tid; i < NT; i += 1024) {
        unsigned u = __float_as_uint(lg[i]);
        u ^= (u >> 31) ? 0xFFFFFFFFu : 0x80000000u;
        key[i] = u;
    }
    if (tid == 0) { sh_pref = 0u; sh_r = NKK; }
    if (tid < 256) hist[tid] = 0u;
    __syncthreads();
    // 4 x 8-bit radix passes, high bits first: find exact 512th-largest key
    unsigned prefmask = 0u;
#pragma unroll
    for (int pass = 0; pass < 4; ++pass) {
        int shift = 24 - 8 * pass;
        unsigned pm = prefmask, pref = sh_pref;
        for (int i = tid; i < NT; i += 1024) {
            unsigned kk = key[i];
            if ((kk & pm) == pref) atomicAdd(&hist[(kk >> shift) & 255u], 1u);
        }
        __syncthreads();
        if (tid == 0) {
            unsigned r = sh_r, cum = 0;
            for (int bin = 255; bin >= 0; --bin) {
                unsigned c = hist[bin];
                if (cum + c >= r) {
                    sh_pref = pref | ((unsigned)bin << shift);
                    sh_r = r - cum;
                    break;
                }
                cum += c;
            }
        }
        __syncthreads();
        if (tid < 256) hist[tid] = 0u;
        prefmask |= (255u << shift);
        __syncthreads();
    }
    unsigned kstar = sh_pref;   // value of the 512th largest
    unsigned r2 = sh_r;         // how many ties (== kstar) to take, smallest idx first
    // per-thread 4 contiguous elements -> index-ordered scans
    int base = tid * 4;
    unsigned g_loc[4], t_loc[4];
    unsigned tsum = 0;
#pragma unroll
    for (int j = 0; j < 4; ++j) {
        unsigned kk = key[base + j];
        g_loc[j] = (kk > kstar) ? 1u : 0u;
        t_loc[j] = (kk == kstar) ? 1u : 0u;
        tsum += t_loc[j];
    }
    // scan 1: tie ranks
    unsigned x = tsum;
#pragma unroll
    for (int off = 1; off < 64; off <<= 1) {
        unsigned v = __shfl_up(x, off);
        if (lane >= off) x += v;
    }
    if (lane == 63) wsum[wv] = x;
    __syncthreads();
    if (tid == 0) {
        unsigned run = 0;
        for (int i = 0; i < 16; ++i) { unsigned t = wsum[i]; wsum[i] = run; run += t; }
    }
    __syncthreads();
    unsigned tie_run = wsum[wv] + x - tsum;
    unsigned s_loc[4], ssum = 0;
#pragma unroll
    for (int j = 0; j < 4; ++j) {
        unsigned sel = g_loc[j] | (t_loc[j] & ((tie_run < r2) ? 1u : 0u));
        tie_run += t_loc[j];
        s_loc[j] = sel;
        ssum += sel;
    }
    __syncthreads();
    // scan 2: selection compaction positions
    unsigned y = ssum;
#pragma unroll
    for (int off = 1; off < 64; off <<= 1) {
        unsigned v = __shfl_up(y, off);
        if (lane >= off) y += v;
    }
    if (lane == 63) wsum[wv] = y;
    __syncthreads();
    if (tid == 0) {
        unsigned run = 0;
        for (int i = 0; i < 16; ++i) { unsigned t = wsum[i]; wsum[i] = run; run += t; }
    }
    __syncthreads();
    unsigned pos = wsum[wv] + y - ssum;
    float lsum = 0.f;
#pragma unroll
    for (int j = 0; j < 4; ++j) {
        if (s_loc[j]) {
            int gi = base + j;
            float l = lg[gi];
            idxv[b * NKK + pos] = gi;
            gates[b * NKK + pos] = 1.f / (1.f + expf(-l));
            lsum += l;
            ++pos;
        }
    }
    for (int off = 32; off; off >>= 1) lsum += __shfl_down(lsum, off);
    if (lane == 0) red[wv] = lsum;
    __syncthreads();
    if (tid == 0) {
        float t = 0.f;
        for (int i = 0; i < 16; ++i) t += red[i];
        atomicAdd(S2, t);
    }
}

// ---------------- aux loss: reduce router partials, subtract selected-logit sum ----
__global__ __launch_bounds__(1024)
void aux_kernel(const float* __restrict__ partials, const float* __restrict__ S2,
                float* __restrict__ outp)
{
    int tid = threadIdx.x, lane = tid & 63, wv = tid >> 6;
    float s = 0.f;
    for (int i = tid; i < 4096; i += 1024) s += partials[i];
    for (int off = 32; off; off >>= 1) s += __shfl_down(s, off);
    __shared__ float red[16];
    if (lane == 0) red[wv] = s;
    __syncthreads();
    if (tid == 0) {
        float t = 0.f;
        for (int i = 0; i < 16; ++i) t += red[i];
        outp[0] = (t - S2[0]) * (0.01f / (float)(NB * NT));
    }
}

// ---------------- weight transpose + bf16 convert: dst[N][K] = src[K][N] ----------------
__global__ __launch_bounds__(256)
void transpose_conv(const float* __restrict__ src, u16* __restrict__ dst,
                    int K, int N)
{
    __shared__ u16 T[64][68];
    int n0 = blockIdx.x * 64, k0 = blockIdx.y * 64;
    int tid = threadIdx.x;
#pragma unroll
    for (int it = 0; it < 4; ++it) {
        int slot = it * 256 + tid;
        int k = slot >> 4, n4 = (slot & 15) * 4;
        float4 v = *(const float4*)&src[(size_t)(k0 + k) * N + n0 + n4];
        u16x4 o = { f2b(v.x), f2b(v.y), f2b(v.z), f2b(v.w) };
        *(u16x4*)&T[k][n4] = o;
    }
    __syncthreads();
#pragma unroll
    for (int it = 0; it < 2; ++it) {
        int slot = it * 256 + tid;
        int n = slot >> 3, k8 = (slot & 7) * 8;
        s16x8 o;
#pragma unroll
        for (int i = 0; i < 8; ++i) o[i] = (short)T[k8 + i][n];
        *(s16x8*)&dst[(size_t)(n0 + n) * K + k0 + k8] = o;
    }
}

// ---------------- gather + rmsnorm (f32 in, bf16 out) ----------------
template<int GATHER>
__global__ __launch_bounds__(256)
void rms_kernel(const float* __restrict__ src, const int* __restrict__ idxv,
                const float* __restrict__ w, float* __restrict__ xsel,
                u16* __restrict__ outp)
{
    int blk = blockIdx.x, tid = threadIdx.x;
    const float* x;
    if (GATHER) {
        int b = blk >> 9;
        x = src + ((size_t)b * NT + idxv[blk]) * ND;
    } else {
        x = src + (size_t)blk * ND;
    }
    float4 v = *(const float4*)&x[tid * 4];
    float ss = v.x * v.x + v.y * v.y + v.z * v.z + v.w * v.w;
    for (int off = 32; off; off >>= 1) ss += __shfl_down(ss, off);
    __shared__ float wred[4];
    if ((tid & 63) == 0) wred[tid >> 6] = ss;
    __syncthreads();
    float tot = wred[0] + wred[1] + wred[2] + wred[3];
    float scale = rsqrtf(tot * (1.f / (float)ND) + 1e-6f);
    float4 wv = *(const float4*)&w[tid * 4];
    u16x4 o = { f2b(v.x * scale * wv.x), f2b(v.y * scale * wv.y),
                f2b(v.z * scale * wv.z), f2b(v.w * scale * wv.w) };
    *(u16x4*)&outp[(size_t)blk * ND + tid * 4] = o;
    if (GATHER) *(float4*)&xsel[(size_t)blk * ND + tid * 4] = v;
}

// ---------------- bf16 MFMA GEMM: C[M][N] = A[M][K] * B^T  (B given as [N][K]) ----
// EPI 1: C bf16   EPI 2: C f32 = acc + P1   EPI 3: gated scatter to outp
#define LPAD 40
template<int EPI>
__global__ __launch_bounds__(256)
void gemm_bt(const u16* __restrict__ A, const u16* __restrict__ B,
             void* __restrict__ Cv, int K, int lda, int ldb, int ldc,
             const float* __restrict__ P1, const float* __restrict__ P2,
             const float* __restrict__ gates, const int* __restrict__ idxv,
             float* __restrict__ outp)
{
    __shared__ u16 As[128 * LPAD];
    __shared__ u16 Bs[128 * LPAD];
    int tid = threadIdx.x, lane = tid & 63, w = tid >> 6;
    int wr = w >> 1, wc = w & 1;
    int bm = blockIdx.y * 128, bn = blockIdx.x * 128;
    int arow = tid >> 2, acol = (tid & 3) * 8;
    const u16* Ap = A + (size_t)(bm + arow) * lda + acol;
    const u16* Ap2 = Ap + (size_t)64 * lda;
    const u16* Bp = B + (size_t)(bn + arow) * ldb + acol;
    const u16* Bp2 = Bp + (size_t)64 * ldb;
    int c15 = lane & 15, ks8 = (lane >> 4) * 8;
    int aoff[4], boff[4];
#pragma unroll
    for (int m2 = 0; m2 < 4; ++m2) aoff[m2] = (wr * 64 + m2 * 16 + c15) * LPAD + ks8;
#pragma unroll
    for (int n2 = 0; n2 < 4; ++n2) boff[n2] = (wc * 64 + n2 * 16 + c15) * LPAD + ks8;
    f32x4 acc[4][4] = {};
    for (int k0 = 0; k0 < K; k0 += 32) {
        s16x8 a0 = *(const s16x8*)(Ap + k0);
        s16x8 a1 = *(const s16x8*)(Ap2 + k0);
        s16x8 b0 = *(const s16x8*)(Bp + k0);
        s16x8 b1 = *(const s16x8*)(Bp2 + k0);
        __syncthreads();
        *(s16x8*)&As[arow * LPAD + acol] = a0;
        *(s16x8*)&As[(arow + 64) * LPAD + acol] = a1;
        *(s16x8*)&Bs[arow * LPAD + acol] = b0;
        *(s16x8*)&Bs[(arow + 64) * LPAD + acol] = b1;
        __syncthreads();
        bf16x8 af[4], bfr[4];
#pragma unroll
        for (int m2 = 0; m2 < 4; ++m2) af[m2] = *(const bf16x8*)&As[aoff[m2]];
#pragma unroll
        for (int n2 = 0; n2 < 4; ++n2) bfr[n2] = *(const bf16x8*)&Bs[boff[n2]];
#pragma unroll
        for (int m2 = 0; m2 < 4; ++m2)
#pragma unroll
            for (int n2 = 0; n2 < 4; ++n2)
                acc[m2][n2] = __builtin_amdgcn_mfma_f32_16x16x32_bf16(
                    af[m2], bfr[n2], acc[m2][n2], 0, 0, 0);
    }
    int r4 = (lane >> 4) * 4;
#pragma unroll
    for (int m2 = 0; m2 < 4; ++m2) {
#pragma unroll
        for (int n2 = 0; n2 < 4; ++n2) {
            f32x4 v = acc[m2][n2];
            int c = bn + wc * 64 + n2 * 16 + c15;
            int r0 = bm + wr * 64 + m2 * 16 + r4;
#pragma unroll
            for (int j = 0; j < 4; ++j) {
                int r = r0 + j;
                float val = v[j];
                if (EPI == 1) {
                    ((u16*)Cv)[(size_t)r * ldc + c] = f2b(val);
                } else if (EPI == 2) {
                    ((float*)Cv)[(size_t)r * ldc + c] = val + P1[(size_t)r * ldc + c];
                } else {
                    float x1v = P1[(size_t)r * ND + c];
                    float xs  = P2[(size_t)r * ND + c];
                    float g = gates[r];
                    float ns = xs + g * (x1v + val - xs);
                    int bb = r >> 9;
                    int tok = idxv[r];
                    outp[((size_t)bb * NT + tok) * ND + c] = ns;
                }
            }
        }
    }
}

// ---------------- RoPE on bf16 q,k (cols 0..2047 of qkv), in place ----------------
__global__ __launch_bounds__(256)
void rope_kernel(u16* __restrict__ qkv, const int* __restrict__ idxv)
{
    int row = blockIdx.x;
    float pos = (float)idxv[row];
    int tid = threadIdx.x;
    for (int p = tid; p < 1024; p += 256) {
        int sec = p >> 9, h = (p >> 5) & 15, j = p & 31;
        float inv = expf(-(float)j * 0.28782313662f);   // ln(10000)/32
        float ang = pos * inv;
        float s = sinf(ang), c = cosf(ang);
        size_t base = (size_t)row * 3072 + sec * 1024 + h * 64 + j;
        float x1 = b2f(qkv[base]), x2 = b2f(qkv[base + 32]);
        qkv[base] = f2b(x1 * c - x2 * s);
        qkv[base + 32] = f2b(x2 * c + x1 * s);
    }
}

// ---------------- flash attention (bf16 MFMA, online softmax) ----------------
__global__ __launch_bounds__(256)
void flash_attn(const u16* __restrict__ qkv, u16* __restrict__ ao)
{
    __shared__ u16 Qs[128 * 72];
    __shared__ u16 Ks[64 * 72];
    __shared__ u16 Vt[64 * 72];
    __shared__ u16 Ps[128 * 72];
    int qt = blockIdx.x, h = blockIdx.y, b = blockIdx.z;
    int tid = threadIdx.x, lane = tid & 63, w = tid >> 6;
    size_t rowbase = (size_t)b * NKK;
    int c15 = lane & 15, ks8 = (lane >> 4) * 8, r4 = (lane >> 4) * 4;
#pragma unroll
    for (int it = 0; it < 4; ++it) {
        int slot = it * 256 + tid;
        int r = slot >> 3, c8 = (slot & 7) * 8;
        s16x8 qv = *(const s16x8*)&qkv[(rowbase + qt * 128 + r) * 3072 + h * 64 + c8];
        *(s16x8*)&Qs[r * 72 + c8] = qv;
    }
    float m_run[2][4], l_run[2][4];
#pragma unroll
    for (int m2 = 0; m2 < 2; ++m2)
#pragma unroll
        for (int j = 0; j < 4; ++j) { m_run[m2][j] = -1e30f; l_run[m2][j] = 0.f; }
    f32x4 oacc[2][4] = {};
    int q0w = qt * 128 + w * 32;
    int nkt = (qt + 1) * 2;
    for (int kt = 0; kt < nkt; ++kt) {
        __syncthreads();
#pragma unroll
        for (int it = 0; it < 2; ++it) {
            int slot = it * 256 + tid;
            int r = slot >> 3, c8 = (slot & 7) * 8;
            s16x8 kv_ = *(const s16x8*)&qkv[(rowbase + kt * 64 + r) * 3072 + 1024 + h * 64 + c8];
            *(s16x8*)&Ks[r * 72 + c8] = kv_;
        }
#pragma unroll
        for (int it = 0; it < 2; ++it) {
            int slot = it * 256 + tid;
            int r = slot >> 3, c8 = (slot & 7) * 8;
            s16x8 vv = *(const s16x8*)&qkv[(rowbase + kt * 64 + r) * 3072 + 2048 + h * 64 + c8];
#pragma unroll
            for (int i = 0; i < 8; ++i) Vt[(c8 + i) * 72 + r] = (u16)vv[i];
        }
        __syncthreads();
        if (kt * 64 <= q0w + 31) {
            f32x4 sacc[2][4] = {};
#pragma unroll
            for (int ks = 0; ks < 2; ++ks) {
                bf16x8 af[2], bfr[4];
#pragma unroll
                for (int m2 = 0; m2 < 2; ++m2)
                    af[m2] = *(const bf16x8*)&Qs[(w * 32 + m2 * 16 + c15) * 72 + ks * 32 + ks8];
#pragma unroll
                for (int n2 = 0; n2 < 4; ++n2)
                    bfr[n2] = *(const bf16x8*)&Ks[(n2 * 16 + c15) * 72 + ks * 32 + ks8];
#pragma unroll
                for (int m2 = 0; m2 < 2; ++m2)
#pragma unroll
                    for (int n2 = 0; n2 < 4; ++n2)
                        sacc[m2][n2] = __builtin_amdgcn_mfma_f32_16x16x32_bf16(
                            af[m2], bfr[n2], sacc[m2][n2], 0, 0, 0);
            }
#pragma unroll
            for (int m2 = 0; m2 < 2; ++m2) {
#pragma unroll
                for (int j = 0; j < 4; ++j) {
                    int rowv = q0w + m2 * 16 + r4 + j;
                    float sv[4];
#pragma unroll
                    for (int n2 = 0; n2 < 4; ++n2) {
                        int colv = kt * 64 + n2 * 16 + c15;
                        float s = sacc[m2][n2][j] * 0.125f;
                        sv[n2] = (colv > rowv) ? -1e30f : s;
                    }
                    float mx = fmaxf(fmaxf(sv[0], sv[1]), fmaxf(sv[2], sv[3]));
                    mx = fmaxf(mx, __shfl_xor(mx, 1));
                    mx = fmaxf(mx, __shfl_xor(mx, 2));
                    mx = fmaxf(mx, __shfl_xor(mx, 4));
                    mx = fmaxf(mx, __shfl_xor(mx, 8));
                    float newm = fmaxf(m_run[m2][j], mx);
                    float alpha = __expf(m_run[m2][j] - newm);
                    m_run[m2][j] = newm;
                    float ls = 0.f;
                    int prow = w * 32 + m2 * 16 + r4 + j;
#pragma unroll
                    for (int n2 = 0; n2 < 4; ++n2) {
                        float pexp = __expf(sv[n2] - newm);
                        ls += pexp;
                        Ps[prow * 72 + n2 * 16 + c15] = f2b(pexp);
                    }
                    ls += __shfl_xor(ls, 1);
                    ls += __shfl_xor(ls, 2);
                    ls += __shfl_xor(ls, 4);
                    ls += __shfl_xor(ls, 8);
                    l_run[m2][j] = l_run[m2][j] * alpha + ls;
#pragma unroll
                    for (int n2 = 0; n2 < 4; ++n2) oacc[m2][n2][j] *= alpha;
                }
            }
#pragma unroll
            for (int ks = 0; ks < 2; ++ks) {
                bf16x8 pa[2], vb[4];
#pragma unroll
                for (int m2 = 0; m2 < 2; ++m2)
                    pa[m2] = *(const bf16x8*)&Ps[(w * 32 + m2 * 16 + c15) * 72 + ks * 32 + ks8];
#pragma unroll
                for (int n2 = 0; n2 < 4; ++n2)
                    vb[n2] = *(const bf16x8*)&Vt[(n2 * 16 + c15) * 72 + ks * 32 + ks8];
#pragma unroll
                for (int m2 = 0; m2 < 2; ++m2)
#pragma unroll
                    for (int n2 = 0; n2 < 4; ++n2)
                        oacc[m2][n2] = __builtin_amdgcn_mfma_f32_16x16x32_bf16(
                            pa[m2], vb[n2], oacc[m2][n2], 0, 0, 0);
            }
        }
    }
#pragma unroll
    for (int m2 = 0; m2 < 2; ++m2) {
#pragma unroll
        for (int j = 0; j < 4; ++j) {
            float invl = 1.f / l_run[m2][j];
            size_t r = rowbase + q0w + m2 * 16 + r4 + j;
#pragma unroll
            for (int n2 = 0; n2 < 4; ++n2)
                ao[r * ND + h * 64 + n2 * 16 + c15] = f2b(oacc[m2][n2][j] * invl);
        }
    }
}

// ---------------- dual GEMM gate/up with fused SiLU (bf16 MFMA) ----------------
__global__ __launch_bounds__(256)
void dual_gemm_silu(const u16* __restrict__ A, const u16* __restrict__ Bw,
                    u16* __restrict__ act)
{
    __shared__ u16 As[128 * LPAD];
    __shared__ u16 Bg[64 * LPAD];
    __shared__ u16 Bu[64 * LPAD];
    int tid = threadIdx.x, lane = tid & 63, w = tid >> 6;
    int bm = blockIdx.y * 128, bn = blockIdx.x * 64;
    int arow = tid >> 2, acol = (tid & 3) * 8;
    const u16* Ap = A + (size_t)(bm + arow) * ND + acol;
    const u16* Ap2 = Ap + (size_t)64 * ND;
    const u16* Gp = Bw + (size_t)(bn + arow) * ND + acol;
    const u16* Up = Bw + (size_t)(NFF + bn + arow) * ND + acol;
    int c15 = lane & 15, ks8 = (lane >> 4) * 8;
    int aoff[2], boff[4];
#pragma unroll
    for (int m2 = 0; m2 < 2; ++m2) aoff[m2] = (w * 32 + m2 * 16 + c15) * LPAD + ks8;
#pragma unroll
    for (int n2 = 0; n2 < 4; ++n2) boff[n2] = (n2 * 16 + c15) * LPAD + ks8;
    f32x4 accg[2][4] = {}, accu[2][4] = {};
    for (int k0 = 0; k0 < ND; k0 += 32) {
        s16x8 a0 = *(const s16x8*)(Ap + k0);
        s16x8 a1 = *(const s16x8*)(Ap2 + k0);
        s16x8 g0 = *(const s16x8*)(Gp + k0);
        s16x8 u0 = *(const s16x8*)(Up + k0);
        __syncthreads();
        *(s16x8*)&As[arow * LPAD + acol] = a0;
        *(s16x8*)&As[(arow + 64) * LPAD + acol] = a1;
        *(s16x8*)&Bg[arow * LPAD + acol] = g0;
        *(s16x8*)&Bu[arow * LPAD + acol] = u0;
        __syncthreads();
        bf16x8 af[2], gf[4], uf[4];
#pragma unroll
        for (int m2 = 0; m2 < 2; ++m2) af[m2] = *(const bf16x8*)&As[aoff[m2]];
#pragma unroll
        for (int n2 = 0; n2 < 4; ++n2) { gf[n2] = *(const bf16x8*)&Bg[boff[n2]];
                                         uf[n2] = *(const bf16x8*)&Bu[boff[n2]]; }
#pragma unroll
        for (int m2 = 0; m2 < 2; ++m2)
#pragma unroll
            for (int n2 = 0; n2 < 4; ++n2) {
                accg[m2][n2] = __builtin_amdgcn_mfma_f32_16x16x32_bf16(
                    af[m2], gf[n2], accg[m2][n2], 0, 0, 0);
                accu[m2][n2] = __builtin_amdgcn_mfma_f32_16x16x32_bf16(
                    af[m2], uf[n2], accu[m2][n2], 0, 0, 0);
            }
    }
    int r4 = (lane >> 4) * 4;
#pragma unroll
    for (int m2 = 0; m2 < 2; ++m2)
#pragma unroll
        for (int n2 = 0; n2 < 4; ++n2)
#pragma unroll
            for (int j = 0; j < 4; ++j) {
                float g = accg[m2][n2][j], uu = accu[m2][n2][j];
                float a = g / (1.f + __expf(-g)) * uu;
                int r = bm + w * 32 + m2 * 16 + r4 + j;
                int c = bn + n2 * 16 + c15;
                act[(size_t)r * NFF + c] = f2b(a);
            }
}

extern "C" void kernel_launch(void* const* d_in, const int* in_sizes, int n_in,
                              void* d_out, int out_size, void* d_ws, size_t ws_size,
                              hipStream_t stream)
{
    const float* hs  = (const float*)d_in[0];
    const float* wr  = (const float*)d_in[1];
    const float* wq  = (const float*)d_in[2];
    const float* wk  = (const float*)d_in[3];
    const float* wv  = (const float*)d_in[4];
    const float* wo  = (const float*)d_in[5];
    const float* ln1 = (const float*)d_in[6];
    const float* ln2 = (const float*)d_in[7];
    const float* wg  = (const float*)d_in[8];
    const float* wu  = (const float*)d_in[9];
    const float* wd  = (const float*)d_in[10];
    float* out = (float*)d_out;
    char* w8 = (char*)d_ws;

    // ---- workspace layout (~76 MB) ----
    float* logits   = (float*)w8;                     // 16384 f
    float* partials = logits + 16384;                 // 4096 f
    float* S2       = partials + 4096;                // 1 f
    int*   idxv  = (int*)(w8 + 0x20000);              // 8 KB
    float* gates = (float*)(w8 + 0x22000);            // 8 KB
    float* xsel  = (float*)(w8 + 0x30000);            // 8 MB
    float* x1b   = xsel + (size_t)NTOK * ND;          // 8 MB
    u16*   hbuf  = (u16*)(x1b + (size_t)NTOK * ND);   // 4 MB (h, then h2)
    u16*   wqkvT = hbuf + (size_t)NTOK * ND;          // 6 MB
    u16*   woT   = wqkvT + (size_t)3072 * 1024;       // 2 MB
    u16*   wguT  = woT + (size_t)1024 * 1024;         // 16 MB
    u16*   wdT   = wguT + (size_t)8192 * 1024;        // 8 MB
    u16*   act   = wdT + (size_t)1024 * 4096;         // 16 MB
    u16*   qkv   = act + (size_t)NTOK * NFF;          // 12 MB
    u16*   ao    = qkv + (size_t)NTOK * 3072;         // 4 MB

    hipMemcpyAsync(out, hs, OUT_MAIN * sizeof(float), hipMemcpyDeviceToDevice, stream);
    hipMemsetAsync(S2, 0, sizeof(float), stream);

    transpose_conv<<<dim3(16, 16), 256, 0, stream>>>(wq, wqkvT, 1024, 1024);
    transpose_conv<<<dim3(16, 16), 256, 0, stream>>>(wk, wqkvT + (size_t)1024 * 1024, 1024, 1024);
    transpose_conv<<<dim3(16, 16), 256, 0, stream>>>(wv, wqkvT + (size_t)2048 * 1024, 1024, 1024);
    transpose_conv<<<dim3(16, 16), 256, 0, stream>>>(wo, woT, 1024, 1024);
    transpose_conv<<<dim3(64, 16), 256, 0, stream>>>(wg, wguT, 1024, 4096);
    transpose_conv<<<dim3(64, 16), 256, 0, stream>>>(wu, wguT + (size_t)4096 * 1024, 1024, 4096);
    transpose_conv<<<dim3(16, 64), 256, 0, stream>>>(wd, wdT, 4096, 1024);

    router_kernel<<<NB * NT / 4, 256, 0, stream>>>(hs, wr, logits, partials);
    topk_kernel<<<NB, 1024, 0, stream>>>(logits, idxv, gates, S2);
    aux_kernel<<<1, 1024, 0, stream>>>(partials, S2, out + OUT_MAIN);

    rms_kernel<1><<<NTOK, 256, 0, stream>>>(hs, idxv, ln1, xsel, hbuf);

    gemm_bt<1><<<dim3(24, 16), 256, 0, stream>>>(
        hbuf, wqkvT, qkv, 1024, 1024, 1024, 3072,
        nullptr, nullptr, nullptr, nullptr, nullptr);

    rope_kernel<<<NTOK, 256, 0, stream>>>(qkv, idxv);

    flash_attn<<<dim3(4, NH, NB), 256, 0, stream>>>(qkv, ao);

    gemm_bt<2><<<dim3(8, 16), 256, 0, stream>>>(
        ao, woT, x1b, 1024, 1024, 1024, 1024,
        xsel, nullptr, nullptr, nullptr, nullptr);

    rms_kernel<0><<<NTOK, 256, 0, stream>>>(x1b, idxv, ln2, nullptr, hbuf);

    dual_gemm_silu<<<dim3(64, 16), 256, 0, stream>>>(hbuf, wguT, act);

    gemm_bt<3><<<dim3(8, 16), 256, 0, stream>>>(
        act, wdT, nullptr, 4096, 4096, 4096, 1024,
        x1b, xsel, gates, idxv, out);
}

// Round 5
// 486.203 us; speedup vs baseline: 4.9369x; 1.0559x over previous
//
#include <hip/hip_runtime.h>
#include <math.h>

#define NB 4
#define NT 4096
#define ND 1024
#define NH 16
#define NDH 64
#define NFF 4096
#define NKK 512
#define NTOK (NB*NKK)                 // 2048
#define OUT_MAIN ((size_t)NB*NT*ND)   // 16777216

typedef unsigned short u16;
typedef __bf16 bf16x8 __attribute__((ext_vector_type(8)));
typedef short  s16x8  __attribute__((ext_vector_type(8)));
typedef unsigned short u16x4 __attribute__((ext_vector_type(4)));
typedef float  f32x4  __attribute__((ext_vector_type(4)));

__device__ inline u16 f2b(float f) {
    unsigned u = __builtin_bit_cast(unsigned, f);
    unsigned r = u + 0x7FFFu + ((u >> 16) & 1u);
    return (u16)(r >> 16);
}
__device__ inline float b2f(u16 v) {
    unsigned u = ((unsigned)v) << 16;
    return __builtin_bit_cast(float, u);
}

// XOR slot swizzles (16B slots). Write and read MUST use the same helper.
// 32-elem (64B) rows: 4 slots; (16*r) bank term + s^((r>>1)&3) covers 8 quads.
__device__ inline int swzA(int r, int s) { return r * 32 + (((s ^ (r >> 1)) & 3) << 3); }
// 64-elem (128B) rows: 8 slots; byte ^= (r&7)<<4 (guide G4 verified form).
__device__ inline int swz64(int r, int s) { return r * 64 + (((s ^ r) & 7) << 3); }

// ---------------- router: logits + per-block softplus partial ----------------
__global__ __launch_bounds__(256)
void router_kernel(const float* __restrict__ hs, const float* __restrict__ wr,
                   float* __restrict__ logits, float* __restrict__ partials)
{
    int wave = threadIdx.x >> 6, lane = threadIdx.x & 63;
    int row = blockIdx.x * 4 + wave;
    const float4* x4 = (const float4*)(hs + (size_t)row * ND);
    const float4* w4 = (const float4*)wr;
    float acc = 0.f;
#pragma unroll
    for (int i = 0; i < 4; ++i) {
        float4 a = x4[lane + i * 64];
        float4 b = w4[lane + i * 64];
        acc += a.x * b.x + a.y * b.y + a.z * b.z + a.w * b.w;
    }
    for (int off = 32; off; off >>= 1) acc += __shfl_down(acc, off);
    __shared__ float sp4[4];
    if (lane == 0) {
        logits[row] = acc;
        sp4[wave] = fmaxf(acc, 0.f) + log1pf(expf(-fabsf(acc)));
    }
    __syncthreads();
    if (threadIdx.x == 0)
        partials[blockIdx.x] = sp4[0] + sp4[1] + sp4[2] + sp4[3];
}

// ---------------- per-batch exact top-k via radix select + compaction ----------------
__global__ __launch_bounds__(1024)
void topk_kernel(const float* __restrict__ logits, int* __restrict__ idxv,
                 float* __restrict__ gates, float* __restrict__ S2)
{
    __shared__ unsigned key[NT];
    __shared__ unsigned hist[256];
    __shared__ unsigned wsum[16];
    __shared__ float red[16];
    __shared__ unsigned sh_pref, sh_r;
    int b = blockIdx.x, tid = threadIdx.x;
    int lane = tid & 63, wv = tid >> 6;
    const float* lg = logits + (size_t)b * NT;
    for (int i = tid; i < NT; i += 1024) {
        unsigned u = __float_as_uint(lg[i]);
        u ^= (u >> 31) ? 0xFFFFFFFFu : 0x80000000u;
        key[i] = u;
    }
    if (tid == 0) { sh_pref = 0u; sh_r = NKK; }
    if (tid < 256) hist[tid] = 0u;
    __syncthreads();
    unsigned prefmask = 0u;
#pragma unroll
    for (int pass = 0; pass < 4; ++pass) {
        int shift = 24 - 8 * pass;
        unsigned pm = prefmask, pref = sh_pref;
        for (int i = tid; i < NT; i += 1024) {
            unsigned kk = key[i];
            if ((kk & pm) == pref) atomicAdd(&hist[(kk >> shift) & 255u], 1u);
        }
        __syncthreads();
        if (tid == 0) {
            unsigned r = sh_r, cum = 0;
            for (int bin = 255; bin >= 0; --bin) {
                unsigned c = hist[bin];
                if (cum + c >= r) {
                    sh_pref = pref | ((unsigned)bin << shift);
                    sh_r = r - cum;
                    break;
                }
                cum += c;
            }
        }
        __syncthreads();
        if (tid < 256) hist[tid] = 0u;
        prefmask |= (255u << shift);
        __syncthreads();
    }
    unsigned kstar = sh_pref;
    unsigned r2 = sh_r;
    int base = tid * 4;
    unsigned g_loc[4], t_loc[4];
    unsigned tsum = 0;
#pragma unroll
    for (int j = 0; j < 4; ++j) {
        unsigned kk = key[base + j];
        g_loc[j] = (kk > kstar) ? 1u : 0u;
        t_loc[j] = (kk == kstar) ? 1u : 0u;
        tsum += t_loc[j];
    }
    unsigned x = tsum;
#pragma unroll
    for (int off = 1; off < 64; off <<= 1) {
        unsigned v = __shfl_up(x, off);
        if (lane >= off) x += v;
    }
    if (lane == 63) wsum[wv] = x;
    __syncthreads();
    if (tid == 0) {
        unsigned run = 0;
        for (int i = 0; i < 16; ++i) { unsigned t = wsum[i]; wsum[i] = run; run += t; }
    }
    __syncthreads();
    unsigned tie_run = wsum[wv] + x - tsum;
    unsigned s_loc[4], ssum = 0;
#pragma unroll
    for (int j = 0; j < 4; ++j) {
        unsigned sel = g_loc[j] | (t_loc[j] & ((tie_run < r2) ? 1u : 0u));
        tie_run += t_loc[j];
        s_loc[j] = sel;
        ssum += sel;
    }
    __syncthreads();
    unsigned y = ssum;
#pragma unroll
    for (int off = 1; off < 64; off <<= 1) {
        unsigned v = __shfl_up(y, off);
        if (lane >= off) y += v;
    }
    if (lane == 63) wsum[wv] = y;
    __syncthreads();
    if (tid == 0) {
        unsigned run = 0;
        for (int i = 0; i < 16; ++i) { unsigned t = wsum[i]; wsum[i] = run; run += t; }
    }
    __syncthreads();
    unsigned pos = wsum[wv] + y - ssum;
    float lsum = 0.f;
#pragma unroll
    for (int j = 0; j < 4; ++j) {
        if (s_loc[j]) {
            int gi = base + j;
            float l = lg[gi];
            idxv[b * NKK + pos] = gi;
            gates[b * NKK + pos] = 1.f / (1.f + expf(-l));
            lsum += l;
            ++pos;
        }
    }
    for (int off = 32; off; off >>= 1) lsum += __shfl_down(lsum, off);
    if (lane == 0) red[wv] = lsum;
    __syncthreads();
    if (tid == 0) {
        float t = 0.f;
        for (int i = 0; i < 16; ++i) t += red[i];
        atomicAdd(S2, t);
    }
}

// ---------------- aux loss ----------------
__global__ __launch_bounds__(1024)
void aux_kernel(const float* __restrict__ partials, const float* __restrict__ S2,
                float* __restrict__ outp)
{
    int tid = threadIdx.x, lane = tid & 63, wv = tid >> 6;
    float s = 0.f;
    for (int i = tid; i < 4096; i += 1024) s += partials[i];
    for (int off = 32; off; off >>= 1) s += __shfl_down(s, off);
    __shared__ float red[16];
    if (lane == 0) red[wv] = s;
    __syncthreads();
    if (tid == 0) {
        float t = 0.f;
        for (int i = 0; i < 16; ++i) t += red[i];
        outp[0] = (t - S2[0]) * (0.01f / (float)(NB * NT));
    }
}

// ---------------- weight transpose + bf16 convert: dst[N][K] = src[K][N] ----------------
__global__ __launch_bounds__(256)
void transpose_conv(const float* __restrict__ src, u16* __restrict__ dst,
                    int K, int N)
{
    __shared__ u16 T[64][68];
    int n0 = blockIdx.x * 64, k0 = blockIdx.y * 64;
    int tid = threadIdx.x;
#pragma unroll
    for (int it = 0; it < 4; ++it) {
        int slot = it * 256 + tid;
        int k = slot >> 4, n4 = (slot & 15) * 4;
        float4 v = *(const float4*)&src[(size_t)(k0 + k) * N + n0 + n4];
        u16x4 o = { f2b(v.x), f2b(v.y), f2b(v.z), f2b(v.w) };
        *(u16x4*)&T[k][n4] = o;
    }
    __syncthreads();
#pragma unroll
    for (int it = 0; it < 2; ++it) {
        int slot = it * 256 + tid;
        int n = slot >> 3, k8 = (slot & 7) * 8;
        s16x8 o;
#pragma unroll
        for (int i = 0; i < 8; ++i) o[i] = (short)T[k8 + i][n];
        *(s16x8*)&dst[(size_t)(n0 + n) * K + k0 + k8] = o;
    }
}

// ---------------- gather + rmsnorm (f32 in, bf16 out) ----------------
template<int GATHER>
__global__ __launch_bounds__(256)
void rms_kernel(const float* __restrict__ src, const int* __restrict__ idxv,
                const float* __restrict__ w, float* __restrict__ xsel,
                u16* __restrict__ outp)
{
    int blk = blockIdx.x, tid = threadIdx.x;
    const float* x;
    if (GATHER) {
        int b = blk >> 9;
        x = src + ((size_t)b * NT + idxv[blk]) * ND;
    } else {
        x = src + (size_t)blk * ND;
    }
    float4 v = *(const float4*)&x[tid * 4];
    float ss = v.x * v.x + v.y * v.y + v.z * v.z + v.w * v.w;
    for (int off = 32; off; off >>= 1) ss += __shfl_down(ss, off);
    __shared__ float wred[4];
    if ((tid & 63) == 0) wred[tid >> 6] = ss;
    __syncthreads();
    float tot = wred[0] + wred[1] + wred[2] + wred[3];
    float scale = rsqrtf(tot * (1.f / (float)ND) + 1e-6f);
    float4 wv = *(const float4*)&w[tid * 4];
    u16x4 o = { f2b(v.x * scale * wv.x), f2b(v.y * scale * wv.y),
                f2b(v.z * scale * wv.z), f2b(v.w * scale * wv.w) };
    *(u16x4*)&outp[(size_t)blk * ND + tid * 4] = o;
    if (GATHER) *(float4*)&xsel[(size_t)blk * ND + tid * 4] = v;
}

// ---------------- bf16 MFMA GEMM: C[M][N] = A[M][K] * B^T  (B given as [N][K]) ----
// BM=128, BN in {64,128}, BK=32, 4 waves (2x2).  Swizzled LDS (swzA).
// EPI 1: C bf16   EPI 2: C f32 = acc + P1   EPI 3: gated scatter to outp
template<int EPI, int BN>
__global__ __launch_bounds__(256)
void gemm_bt(const u16* __restrict__ A, const u16* __restrict__ B,
             void* __restrict__ Cv, int K, int lda, int ldb, int ldc,
             const float* __restrict__ P1, const float* __restrict__ P2,
             const float* __restrict__ gates, const int* __restrict__ idxv,
             float* __restrict__ outp)
{
    constexpr int NF = BN / 32;          // n-frags per wave (2 or 4)
    __shared__ u16 As[128 * 32];
    __shared__ u16 Bs[BN * 32];
    int tid = threadIdx.x, lane = tid & 63, w = tid >> 6;
    int wr = w >> 1, wc = w & 1;
    int bm = blockIdx.y * 128, bn = blockIdx.x * BN;
    int arow = tid >> 2, g = tid & 3;    // staging: row, 16B slot
    const u16* Ap  = A + (size_t)(bm + arow) * lda + g * 8;
    const u16* Ap2 = Ap + (size_t)64 * lda;
    const u16* Bp  = B + (size_t)(bn + arow) * ldb + g * 8;
    const u16* Bp2 = Bp + (size_t)64 * ldb;
    int c15 = lane & 15, ksl = lane >> 4;     // fragment: col-in-frag, k-slot
    int aoff[4], boff[NF];
#pragma unroll
    for (int m2 = 0; m2 < 4; ++m2) aoff[m2] = swzA(wr * 64 + m2 * 16 + c15, ksl);
#pragma unroll
    for (int n2 = 0; n2 < NF; ++n2) boff[n2] = swzA(wc * 16 * NF + n2 * 16 + c15, ksl);
    int wa0 = swzA(arow, g), wa1 = swzA(arow + 64, g);
    f32x4 acc[4][NF] = {};
    for (int k0 = 0; k0 < K; k0 += 32) {
        s16x8 a0 = *(const s16x8*)(Ap + k0);
        s16x8 a1 = *(const s16x8*)(Ap2 + k0);
        s16x8 b0 = *(const s16x8*)(Bp + k0);
        s16x8 b1;
        if (BN == 128) b1 = *(const s16x8*)(Bp2 + k0);
        __syncthreads();
        *(s16x8*)&As[wa0] = a0;
        *(s16x8*)&As[wa1] = a1;
        *(s16x8*)&Bs[wa0] = b0;
        if (BN == 128) *(s16x8*)&Bs[wa1] = b1;
        __syncthreads();
        bf16x8 af[4], bfr[NF];
#pragma unroll
        for (int m2 = 0; m2 < 4; ++m2) af[m2] = *(const bf16x8*)&As[aoff[m2]];
#pragma unroll
        for (int n2 = 0; n2 < NF; ++n2) bfr[n2] = *(const bf16x8*)&Bs[boff[n2]];
#pragma unroll
        for (int m2 = 0; m2 < 4; ++m2)
#pragma unroll
            for (int n2 = 0; n2 < NF; ++n2)
                acc[m2][n2] = __builtin_amdgcn_mfma_f32_16x16x32_bf16(
                    af[m2], bfr[n2], acc[m2][n2], 0, 0, 0);
    }
    int r4 = (lane >> 4) * 4;
#pragma unroll
    for (int m2 = 0; m2 < 4; ++m2) {
#pragma unroll
        for (int n2 = 0; n2 < NF; ++n2) {
            f32x4 v = acc[m2][n2];
            int c = bn + wc * 16 * NF + n2 * 16 + c15;
            int r0 = bm + wr * 64 + m2 * 16 + r4;
#pragma unroll
            for (int j = 0; j < 4; ++j) {
                int r = r0 + j;
                float val = v[j];
                if (EPI == 1) {
                    ((u16*)Cv)[(size_t)r * ldc + c] = f2b(val);
                } else if (EPI == 2) {
                    ((float*)Cv)[(size_t)r * ldc + c] = val + P1[(size_t)r * ldc + c];
                } else {
                    float x1v = P1[(size_t)r * ND + c];
                    float xs  = P2[(size_t)r * ND + c];
                    float gt = gates[r];
                    float ns = xs + gt * (x1v + val - xs);
                    int bb = r >> 9;
                    int tok = idxv[r];
                    outp[((size_t)bb * NT + tok) * ND + c] = ns;
                }
            }
        }
    }
}

// ---------------- RoPE on bf16 q,k (cols 0..2047 of qkv), in place ----------------
__global__ __launch_bounds__(256)
void rope_kernel(u16* __restrict__ qkv, const int* __restrict__ idxv)
{
    int row = blockIdx.x;
    float pos = (float)idxv[row];
    int tid = threadIdx.x;
    for (int p = tid; p < 1024; p += 256) {
        int sec = p >> 9, h = (p >> 5) & 15, j = p & 31;
        float inv = expf(-(float)j * 0.28782313662f);   // ln(10000)/32
        float ang = pos * inv;
        float s = sinf(ang), c = cosf(ang);
        size_t base = (size_t)row * 3072 + sec * 1024 + h * 64 + j;
        float x1 = b2f(qkv[base]), x2 = b2f(qkv[base + 32]);
        qkv[base] = f2b(x1 * c - x2 * s);
        qkv[base + 32] = f2b(x2 * c + x1 * s);
    }
}

// ---------------- flash attention (bf16 MFMA, online softmax, swizzled LDS) ----------------
__global__ __launch_bounds__(256)
void flash_attn(const u16* __restrict__ qkv, u16* __restrict__ ao)
{
    __shared__ u16 Qs[128 * 64];
    __shared__ u16 Ks[64 * 64];
    __shared__ u16 Vt[64 * 64];
    __shared__ u16 Ps[128 * 64];
    int qt = blockIdx.x, h = blockIdx.y, b = blockIdx.z;
    int tid = threadIdx.x, lane = tid & 63, w = tid >> 6;
    size_t rowbase = (size_t)b * NKK;
    int c15 = lane & 15, ksl = lane >> 4, r4 = (lane >> 4) * 4;
#pragma unroll
    for (int it = 0; it < 4; ++it) {
        int slot = it * 256 + tid;
        int r = slot >> 3, s = slot & 7;
        s16x8 qv = *(const s16x8*)&qkv[(rowbase + qt * 128 + r) * 3072 + h * 64 + s * 8];
        *(s16x8*)&Qs[swz64(r, s)] = qv;
    }
    float m_run[2][4], l_run[2][4];
#pragma unroll
    for (int m2 = 0; m2 < 2; ++m2)
#pragma unroll
        for (int j = 0; j < 4; ++j) { m_run[m2][j] = -1e30f; l_run[m2][j] = 0.f; }
    f32x4 oacc[2][4] = {};
    int q0w = qt * 128 + w * 32;
    int nkt = (qt + 1) * 2;
    for (int kt = 0; kt < nkt; ++kt) {
        __syncthreads();
#pragma unroll
        for (int it = 0; it < 2; ++it) {
            int slot = it * 256 + tid;
            int r = slot >> 3, s = slot & 7;
            s16x8 kv_ = *(const s16x8*)&qkv[(rowbase + kt * 64 + r) * 3072 + 1024 + h * 64 + s * 8];
            *(s16x8*)&Ks[swz64(r, s)] = kv_;
        }
#pragma unroll
        for (int it = 0; it < 2; ++it) {
            int slot = it * 256 + tid;
            int r = slot >> 3, s = slot & 7;
            s16x8 vv = *(const s16x8*)&qkv[(rowbase + kt * 64 + r) * 3072 + 2048 + h * 64 + s * 8];
#pragma unroll
            for (int i = 0; i < 8; ++i) {
                int vr = s * 8 + i;     // d-dim row of Vt
                Vt[vr * 64 + ((((r >> 3) ^ vr) & 7) << 3) + (r & 7)] = (u16)vv[i];
            }
        }
        __syncthreads();
        if (kt * 64 <= q0w + 31) {
            f32x4 sacc[2][4] = {};
#pragma unroll
            for (int ks = 0; ks < 2; ++ks) {
                bf16x8 af[2], bfr[4];
#pragma unroll
                for (int m2 = 0; m2 < 2; ++m2)
                    af[m2] = *(const bf16x8*)&Qs[swz64(w * 32 + m2 * 16 + c15, ks * 4 + ksl)];
#pragma unroll
                for (int n2 = 0; n2 < 4; ++n2)
                    bfr[n2] = *(const bf16x8*)&Ks[swz64(n2 * 16 + c15, ks * 4 + ksl)];
#pragma unroll
                for (int m2 = 0; m2 < 2; ++m2)
#pragma unroll
                    for (int n2 = 0; n2 < 4; ++n2)
                        sacc[m2][n2] = __builtin_amdgcn_mfma_f32_16x16x32_bf16(
                            af[m2], bfr[n2], sacc[m2][n2], 0, 0, 0);
            }
#pragma unroll
            for (int m2 = 0; m2 < 2; ++m2) {
#pragma unroll
                for (int j = 0; j < 4; ++j) {
                    int rowv = q0w + m2 * 16 + r4 + j;
                    float sv[4];
#pragma unroll
                    for (int n2 = 0; n2 < 4; ++n2) {
                        int colv = kt * 64 + n2 * 16 + c15;
                        float s = sacc[m2][n2][j] * 0.125f;
                        sv[n2] = (colv > rowv) ? -1e30f : s;
                    }
                    float mx = fmaxf(fmaxf(sv[0], sv[1]), fmaxf(sv[2], sv[3]));
                    mx = fmaxf(mx, __shfl_xor(mx, 1));
                    mx = fmaxf(mx, __shfl_xor(mx, 2));
                    mx = fmaxf(mx, __shfl_xor(mx, 4));
                    mx = fmaxf(mx, __shfl_xor(mx, 8));
                    float newm = fmaxf(m_run[m2][j], mx);
                    float alpha = __expf(m_run[m2][j] - newm);
                    m_run[m2][j] = newm;
                    float ls = 0.f;
                    int prow = w * 32 + m2 * 16 + r4 + j;
#pragma unroll
                    for (int n2 = 0; n2 < 4; ++n2) {
                        float pexp = __expf(sv[n2] - newm);
                        ls += pexp;
                        int c = n2 * 16 + c15;
                        Ps[prow * 64 + ((((c >> 3) ^ prow) & 7) << 3) + (c & 7)] = f2b(pexp);
                    }
                    ls += __shfl_xor(ls, 1);
                    ls += __shfl_xor(ls, 2);
                    ls += __shfl_xor(ls, 4);
                    ls += __shfl_xor(ls, 8);
                    l_run[m2][j] = l_run[m2][j] * alpha + ls;
#pragma unroll
                    for (int n2 = 0; n2 < 4; ++n2) oacc[m2][n2][j] *= alpha;
                }
            }
#pragma unroll
            for (int ks = 0; ks < 2; ++ks) {
                bf16x8 pa[2], vb[4];
#pragma unroll
                for (int m2 = 0; m2 < 2; ++m2)
                    pa[m2] = *(const bf16x8*)&Ps[swz64(w * 32 + m2 * 16 + c15, ks * 4 + ksl)];
#pragma unroll
                for (int n2 = 0; n2 < 4; ++n2)
                    vb[n2] = *(const bf16x8*)&Vt[swz64(n2 * 16 + c15, ks * 4 + ksl)];
#pragma unroll
                for (int m2 = 0; m2 < 2; ++m2)
#pragma unroll
                    for (int n2 = 0; n2 < 4; ++n2)
                        oacc[m2][n2] = __builtin_amdgcn_mfma_f32_16x16x32_bf16(
                            pa[m2], vb[n2], oacc[m2][n2], 0, 0, 0);
            }
        }
    }
#pragma unroll
    for (int m2 = 0; m2 < 2; ++m2) {
#pragma unroll
        for (int j = 0; j < 4; ++j) {
            float invl = 1.f / l_run[m2][j];
            size_t r = rowbase + q0w + m2 * 16 + r4 + j;
#pragma unroll
            for (int n2 = 0; n2 < 4; ++n2)
                ao[r * ND + h * 64 + n2 * 16 + c15] = f2b(oacc[m2][n2][j] * invl);
        }
    }
}

// ---------------- dual GEMM gate/up with fused SiLU (bf16 MFMA, swizzled LDS) ----
__global__ __launch_bounds__(256)
void dual_gemm_silu(const u16* __restrict__ A, const u16* __restrict__ Bw,
                    u16* __restrict__ act)
{
    __shared__ u16 As[128 * 32];
    __shared__ u16 Bg[64 * 32];
    __shared__ u16 Bu[64 * 32];
    int tid = threadIdx.x, lane = tid & 63, w = tid >> 6;
    int bm = blockIdx.y * 128, bn = blockIdx.x * 64;
    int arow = tid >> 2, g = tid & 3;
    const u16* Ap  = A + (size_t)(bm + arow) * ND + g * 8;
    const u16* Ap2 = Ap + (size_t)64 * ND;
    const u16* Gp  = Bw + (size_t)(bn + arow) * ND + g * 8;
    const u16* Up  = Bw + (size_t)(NFF + bn + arow) * ND + g * 8;
    int c15 = lane & 15, ksl = lane >> 4;
    int aoff[2], boff[4];
#pragma unroll
    for (int m2 = 0; m2 < 2; ++m2) aoff[m2] = swzA(w * 32 + m2 * 16 + c15, ksl);
#pragma unroll
    for (int n2 = 0; n2 < 4; ++n2) boff[n2] = swzA(n2 * 16 + c15, ksl);
    int wa0 = swzA(arow, g), wa1 = swzA(arow + 64, g);
    f32x4 accg[2][4] = {}, accu[2][4] = {};
    for (int k0 = 0; k0 < ND; k0 += 32) {
        s16x8 a0 = *(const s16x8*)(Ap + k0);
        s16x8 a1 = *(const s16x8*)(Ap2 + k0);
        s16x8 g0 = *(const s16x8*)(Gp + k0);
        s16x8 u0 = *(const s16x8*)(Up + k0);
        __syncthreads();
        *(s16x8*)&As[wa0] = a0;
        *(s16x8*)&As[wa1] = a1;
        *(s16x8*)&Bg[wa0] = g0;
        *(s16x8*)&Bu[wa0] = u0;
        __syncthreads();
        bf16x8 af[2], gf[4], uf[4];
#pragma unroll
        for (int m2 = 0; m2 < 2; ++m2) af[m2] = *(const bf16x8*)&As[aoff[m2]];
#pragma unroll
        for (int n2 = 0; n2 < 4; ++n2) { gf[n2] = *(const bf16x8*)&Bg[boff[n2]];
                                         uf[n2] = *(const bf16x8*)&Bu[boff[n2]]; }
#pragma unroll
        for (int m2 = 0; m2 < 2; ++m2)
#pragma unroll
            for (int n2 = 0; n2 < 4; ++n2) {
                accg[m2][n2] = __builtin_amdgcn_mfma_f32_16x16x32_bf16(
                    af[m2], gf[n2], accg[m2][n2], 0, 0, 0);
                accu[m2][n2] = __builtin_amdgcn_mfma_f32_16x16x32_bf16(
                    af[m2], uf[n2], accu[m2][n2], 0, 0, 0);
            }
    }
    int r4 = (lane >> 4) * 4;
#pragma unroll
    for (int m2 = 0; m2 < 2; ++m2)
#pragma unroll
        for (int n2 = 0; n2 < 4; ++n2)
#pragma unroll
            for (int j = 0; j < 4; ++j) {
                float gg = accg[m2][n2][j], uu = accu[m2][n2][j];
                float a = gg / (1.f + __expf(-gg)) * uu;
                int r = bm + w * 32 + m2 * 16 + r4 + j;
                int c = bn + n2 * 16 + c15;
                act[(size_t)r * NFF + c] = f2b(a);
            }
}

extern "C" void kernel_launch(void* const* d_in, const int* in_sizes, int n_in,
                              void* d_out, int out_size, void* d_ws, size_t ws_size,
                              hipStream_t stream)
{
    const float* hs  = (const float*)d_in[0];
    const float* wr  = (const float*)d_in[1];
    const float* wq  = (const float*)d_in[2];
    const float* wk  = (const float*)d_in[3];
    const float* wv  = (const float*)d_in[4];
    const float* wo  = (const float*)d_in[5];
    const float* ln1 = (const float*)d_in[6];
    const float* ln2 = (const float*)d_in[7];
    const float* wg  = (const float*)d_in[8];
    const float* wu  = (const float*)d_in[9];
    const float* wd  = (const float*)d_in[10];
    float* out = (float*)d_out;
    char* w8 = (char*)d_ws;

    float* logits   = (float*)w8;                     // 16384 f
    float* partials = logits + 16384;                 // 4096 f
    float* S2       = partials + 4096;                // 1 f
    int*   idxv  = (int*)(w8 + 0x20000);              // 8 KB
    float* gates = (float*)(w8 + 0x22000);            // 8 KB
    float* xsel  = (float*)(w8 + 0x30000);            // 8 MB
    float* x1b   = xsel + (size_t)NTOK * ND;          // 8 MB
    u16*   hbuf  = (u16*)(x1b + (size_t)NTOK * ND);   // 4 MB
    u16*   wqkvT = hbuf + (size_t)NTOK * ND;          // 6 MB
    u16*   woT   = wqkvT + (size_t)3072 * 1024;       // 2 MB
    u16*   wguT  = woT + (size_t)1024 * 1024;         // 16 MB
    u16*   wdT   = wguT + (size_t)8192 * 1024;        // 8 MB
    u16*   act   = wdT + (size_t)1024 * 4096;         // 16 MB
    u16*   qkv   = act + (size_t)NTOK * NFF;          // 12 MB
    u16*   ao    = qkv + (size_t)NTOK * 3072;         // 4 MB

    hipMemcpyAsync(out, hs, OUT_MAIN * sizeof(float), hipMemcpyDeviceToDevice, stream);
    hipMemsetAsync(S2, 0, sizeof(float), stream);

    transpose_conv<<<dim3(16, 16), 256, 0, stream>>>(wq, wqkvT, 1024, 1024);
    transpose_conv<<<dim3(16, 16), 256, 0, stream>>>(wk, wqkvT + (size_t)1024 * 1024, 1024, 1024);
    transpose_conv<<<dim3(16, 16), 256, 0, stream>>>(wv, wqkvT + (size_t)2048 * 1024, 1024, 1024);
    transpose_conv<<<dim3(16, 16), 256, 0, stream>>>(wo, woT, 1024, 1024);
    transpose_conv<<<dim3(64, 16), 256, 0, stream>>>(wg, wguT, 1024, 4096);
    transpose_conv<<<dim3(64, 16), 256, 0, stream>>>(wu, wguT + (size_t)4096 * 1024, 1024, 4096);
    transpose_conv<<<dim3(16, 64), 256, 0, stream>>>(wd, wdT, 4096, 1024);

    router_kernel<<<NB * NT / 4, 256, 0, stream>>>(hs, wr, logits, partials);
    topk_kernel<<<NB, 1024, 0, stream>>>(logits, idxv, gates, S2);
    aux_kernel<<<1, 1024, 0, stream>>>(partials, S2, out + OUT_MAIN);

    rms_kernel<1><<<NTOK, 256, 0, stream>>>(hs, idxv, ln1, xsel, hbuf);

    // QKV: [2048,1024] x [1024,3072] -> qkv bf16, 24x16 = 384 blocks
    gemm_bt<1, 128><<<dim3(24, 16), 256, 0, stream>>>(
        hbuf, wqkvT, qkv, 1024, 1024, 1024, 3072,
        nullptr, nullptr, nullptr, nullptr, nullptr);

    rope_kernel<<<NTOK, 256, 0, stream>>>(qkv, idxv);

    flash_attn<<<dim3(4, NH, NB), 256, 0, stream>>>(qkv, ao);

    // x1 = ao @ wo + xsel (f32), 16x16 = 256 blocks
    gemm_bt<2, 64><<<dim3(16, 16), 256, 0, stream>>>(
        ao, woT, x1b, 1024, 1024, 1024, 1024,
        xsel, nullptr, nullptr, nullptr, nullptr);

    rms_kernel<0><<<NTOK, 256, 0, stream>>>(x1b, idxv, ln2, nullptr, hbuf);

    dual_gemm_silu<<<dim3(64, 16), 256, 0, stream>>>(hbuf, wguT, act);

    // mlp = act @ wd; fused gated scatter, 16x16 = 256 blocks
    gemm_bt<3, 64><<<dim3(16, 16), 256, 0, stream>>>(
        act, wdT, nullptr, 4096, 4096, 4096, 1024,
        x1b, xsel, gates, idxv, out);
}